// Round 2
// baseline (1632.094 us; speedup 1.0000x reference)
//
#include <hip/hip_runtime.h>
#include <math.h>

#define BATCH 2
#define SEQ   1024
#define EMB   1024
#define NH    16
#define DH    64
#define BSE   (BATCH*SEQ*EMB)   /* 2097152 elements per (B,S,E) tensor */

// ---------------------------------------------------------------------------
// qc_dense GEMM: M=2048, N=1024, K=1024, fp32 in/out, fp32 accumulate.
//   oa = xa@wa^T + j2*(xb@wb^T) + ba
//   ob = xa@wb^T +     xb@wa^T + bb
// 64x64 output tile / block of 256 threads, 4x4 register micro-tile,
// K staged in 16-wide LDS chunks ([k][m] layout, pad 65 -> conflict-free).
// ---------------------------------------------------------------------------
__global__ __launch_bounds__(256) void qc_gemm(
    const float* __restrict__ xa, const float* __restrict__ xb,
    const float* __restrict__ wa, const float* __restrict__ wb,
    const float* __restrict__ ba, const float* __restrict__ bb,
    const float* __restrict__ theta,
    float* __restrict__ oa, float* __restrict__ ob)
{
    __shared__ float sXa[16][65];
    __shared__ float sXb[16][65];
    __shared__ float sWa[16][65];
    __shared__ float sWb[16][65];

    const int t  = threadIdx.x;
    const int tx = t & 15;       // output col group
    const int ty = t >> 4;       // output row group
    const int n0 = blockIdx.x * 64;
    const int m0 = blockIdx.y * 64;
    const int lr = t >> 2;       // load row within tile (0..63)
    const int lk = (t & 3) << 2; // load k offset (0,4,8,12)

    float cpp[4][4] = {{0}}, cqq[4][4] = {{0}}, cpq[4][4] = {{0}}, cqp[4][4] = {{0}};

    const float* pxa = xa + (size_t)(m0 + lr) * EMB + lk;
    const float* pxb = xb + (size_t)(m0 + lr) * EMB + lk;
    const float* pwa = wa + (size_t)(n0 + lr) * EMB + lk;
    const float* pwb = wb + (size_t)(n0 + lr) * EMB + lk;

    for (int k0 = 0; k0 < EMB; k0 += 16) {
        __syncthreads();   // protect previous chunk's LDS reads
        float4 uxa = *(const float4*)(pxa + k0);
        float4 uxb = *(const float4*)(pxb + k0);
        float4 uwa = *(const float4*)(pwa + k0);
        float4 uwb = *(const float4*)(pwb + k0);
        sXa[lk+0][lr] = uxa.x; sXa[lk+1][lr] = uxa.y;
        sXa[lk+2][lr] = uxa.z; sXa[lk+3][lr] = uxa.w;
        sXb[lk+0][lr] = uxb.x; sXb[lk+1][lr] = uxb.y;
        sXb[lk+2][lr] = uxb.z; sXb[lk+3][lr] = uxb.w;
        sWa[lk+0][lr] = uwa.x; sWa[lk+1][lr] = uwa.y;
        sWa[lk+2][lr] = uwa.z; sWa[lk+3][lr] = uwa.w;
        sWb[lk+0][lr] = uwb.x; sWb[lk+1][lr] = uwb.y;
        sWb[lk+2][lr] = uwb.z; sWb[lk+3][lr] = uwb.w;
        __syncthreads();

        #pragma unroll
        for (int k = 0; k < 16; ++k) {
            float a_[4], b_[4], u_[4], v_[4];
            #pragma unroll
            for (int i = 0; i < 4; ++i) { a_[i] = sXa[k][ty*4+i]; b_[i] = sXb[k][ty*4+i]; }
            #pragma unroll
            for (int j = 0; j < 4; ++j) { u_[j] = sWa[k][tx*4+j]; v_[j] = sWb[k][tx*4+j]; }
            #pragma unroll
            for (int i = 0; i < 4; ++i) {
                #pragma unroll
                for (int j = 0; j < 4; ++j) {
                    cpp[i][j] += a_[i]*u_[j];
                    cqq[i][j] += b_[i]*v_[j];
                    cpq[i][j] += a_[i]*v_[j];
                    cqp[i][j] += b_[i]*u_[j];
                }
            }
        }
    }

    const float j2 = sinf(2.0f * theta[0]) - 1.0f;
    float bav[4], bbv[4];
    #pragma unroll
    for (int j = 0; j < 4; ++j) {
        const int n = n0 + tx*4 + j;
        bav[j] = ba[n];
        bbv[j] = bb[n];
    }
    #pragma unroll
    for (int i = 0; i < 4; ++i) {
        const int m = m0 + ty*4 + i;
        float4 ra, rb;
        ra.x = cpp[i][0] + j2*cqq[i][0] + bav[0];
        ra.y = cpp[i][1] + j2*cqq[i][1] + bav[1];
        ra.z = cpp[i][2] + j2*cqq[i][2] + bav[2];
        ra.w = cpp[i][3] + j2*cqq[i][3] + bav[3];
        rb.x = cpq[i][0] + cqp[i][0] + bbv[0];
        rb.y = cpq[i][1] + cqp[i][1] + bbv[1];
        rb.z = cpq[i][2] + cqp[i][2] + bbv[2];
        rb.w = cpq[i][3] + cqp[i][3] + bbv[3];
        *(float4*)(oa + (size_t)m*EMB + n0 + tx*4) = ra;
        *(float4*)(ob + (size_t)m*EMB + n0 + tx*4) = rb;
    }
}

// ---------------------------------------------------------------------------
// RoPE, in place on (B,S,E) fp32 where E = H*Dh; pair (d, d+32) within head.
// grid = (B*S*H*32/256, 4 tensors)
// ---------------------------------------------------------------------------
__global__ __launch_bounds__(256) void rope_kernel(
    float* qa, float* qb, float* ka, float* kb)
{
    float* p;
    switch (blockIdx.y) {
        case 0:  p = qa; break;
        case 1:  p = qb; break;
        case 2:  p = ka; break;
        default: p = kb; break;
    }
    const int i   = blockIdx.x * 256 + threadIdx.x; // 0 .. B*S*H*32-1
    const int d   = i & 31;
    const int hh  = (i >> 5) & (NH - 1);
    const int row = i >> 9;            // b*S + s
    const int s   = row & (SEQ - 1);
    const size_t base = (size_t)row * EMB + hh * DH;

    float x1 = p[base + d];
    float x2 = p[base + d + 32];
    const float invf = expf(-(float)d * (9.210340371976184f / 32.0f)); // 10000^(-d/32)
    const float ang  = (float)s * invf;
    float sn, cs;
    sincosf(ang, &sn, &cs);
    p[base + d]      = x1 * cs - x2 * sn;
    p[base + d + 32] = x2 * cs + x1 * sn;
}

// ---------------------------------------------------------------------------
// Flash-style causal attention with complex-magnitude scores.
// Block = 256 threads = 4 waves; each wave owns one q row; block shares
// 64-wide K then V tiles in LDS. Online softmax per wave; lane owns dim d.
//   s_a = qa.ka + j2h*(qb.kb); s_b = qa.kb + qb.ka
//   mag = sqrt(s_a^2+s_b^2+1e-8)/8 ; causal mask ; softmax ; out = P@V
// grid = B*H*(S/4) blocks.
// ---------------------------------------------------------------------------
__global__ __launch_bounds__(256) void attn_kernel(
    const float* __restrict__ qa, const float* __restrict__ qb,
    const float* __restrict__ ka, const float* __restrict__ kb,
    const float* __restrict__ va, const float* __restrict__ vb,
    const float* __restrict__ thetas,
    float* __restrict__ oa, float* __restrict__ ob)
{
    __shared__ float sA[64][66];
    __shared__ float sB[64][66];
    __shared__ float sQa[4][64];
    __shared__ float sQb[4][64];
    __shared__ float sP[4][64];

    const int t   = threadIdx.x;
    const int w   = t >> 6;   // wave id 0..3
    const int L   = t & 63;   // lane
    const int bid = blockIdx.x;
    const int qt  = bid & (SEQ/4 - 1);       // q-tile (4 rows)
    const int bh  = bid / (SEQ/4);
    const int h   = bh & (NH - 1);
    const int b   = bh >> 4;
    const int q   = qt * 4 + w;

    const size_t rowQ = (size_t)(b*SEQ + q) * EMB + h * DH;
    sQa[w][L] = qa[rowQ + L];
    sQb[w][L] = qb[rowQ + L];
    __syncthreads();

    const float j2h = sinf(2.0f * thetas[h]) - 1.0f;

    float m_run = -1e30f, l_run = 0.0f;
    float acc_a = 0.0f, acc_b = 0.0f;

    const int lr = t >> 2;          // tile load row 0..63
    const int d0 = (t & 3) << 4;    // tile load col base (0,16,32,48)
    const int nt = ((qt*4 + 3) >> 6) + 1;  // causal tile count (uniform in block)

    for (int kt = 0; kt < nt; ++kt) {
        const size_t gbase = (size_t)(b*SEQ + kt*64 + lr) * EMB + h * DH + d0;

        // ---- load K tile (ka->sA, kb->sB) ----
        __syncthreads();
        #pragma unroll
        for (int u = 0; u < 16; u += 4) {
            float4 uA = *(const float4*)(ka + gbase + u);
            float4 uB = *(const float4*)(kb + gbase + u);
            const int d = d0 + u;
            sA[lr][d+0] = uA.x; sA[lr][d+1] = uA.y;
            sA[lr][d+2] = uA.z; sA[lr][d+3] = uA.w;
            sB[lr][d+0] = uB.x; sB[lr][d+1] = uB.y;
            sB[lr][d+2] = uB.z; sB[lr][d+3] = uB.w;
        }
        __syncthreads();

        // ---- scores: lane L handles k = kt*64 + L ----
        float s_aa = 0.f, s_bb = 0.f, s_ab = 0.f, s_ba = 0.f;
        #pragma unroll 8
        for (int d = 0; d < 64; ++d) {
            const float qra = sQa[w][d], qrb = sQb[w][d];
            const float kva = sA[L][d],  kvb = sB[L][d];
            s_aa += qra * kva;
            s_bb += qrb * kvb;
            s_ab += qra * kvb;
            s_ba += qrb * kva;
        }
        const float s_a = s_aa + j2h * s_bb;
        const float s_b = s_ab + s_ba;
        float mag = sqrtf(s_a*s_a + s_b*s_b + 1e-8f) * 0.125f;
        const int k = kt*64 + L;
        if (k > q) mag = -1e9f;

        // ---- online softmax (per wave) ----
        float tmax = mag;
        #pragma unroll
        for (int off = 32; off >= 1; off >>= 1)
            tmax = fmaxf(tmax, __shfl_xor(tmax, off, 64));
        const float m_new = fmaxf(m_run, tmax);
        const float p = expf(mag - m_new);
        float psum = p;
        #pragma unroll
        for (int off = 32; off >= 1; off >>= 1)
            psum += __shfl_xor(psum, off, 64);
        const float alpha = expf(m_run - m_new);
        l_run = l_run * alpha + psum;
        m_run = m_new;
        acc_a *= alpha;
        acc_b *= alpha;
        sP[w][L] = p;

        // ---- load V tile (va->sA, vb->sB) ----
        __syncthreads();
        #pragma unroll
        for (int u = 0; u < 16; u += 4) {
            float4 uA = *(const float4*)(va + gbase + u);
            float4 uB = *(const float4*)(vb + gbase + u);
            const int d = d0 + u;
            sA[lr][d+0] = uA.x; sA[lr][d+1] = uA.y;
            sA[lr][d+2] = uA.z; sA[lr][d+3] = uA.w;
            sB[lr][d+0] = uB.x; sB[lr][d+1] = uB.y;
            sB[lr][d+2] = uB.z; sB[lr][d+3] = uB.w;
        }
        __syncthreads();

        // ---- PV: lane L owns output dim d = L ----
        #pragma unroll 8
        for (int kk = 0; kk < 64; ++kk) {
            const float pk = sP[w][kk];
            acc_a += pk * sA[kk][L];
            acc_b += pk * sB[kk][L];
        }
    }

    const float inv_l = 1.0f / l_run;
    oa[rowQ + L] = acc_a * inv_l;
    ob[rowQ + L] = acc_b * inv_l;
}

// ---------------------------------------------------------------------------
extern "C" void kernel_launch(void* const* d_in, const int* in_sizes, int n_in,
                              void* d_out, int out_size, void* d_ws, size_t ws_size,
                              hipStream_t stream)
{
    const float* x_q_a  = (const float*)d_in[0];
    const float* x_q_b  = (const float*)d_in[1];
    const float* x_kv_a = (const float*)d_in[2];
    const float* x_kv_b = (const float*)d_in[3];
    /* d_in[4] = mask (int32 tril) -- causal handled analytically */
    const float* theta    = (const float*)d_in[5];
    const float* thetas_h = (const float*)d_in[6];
    const float* q_wa = (const float*)d_in[7];
    const float* q_wb = (const float*)d_in[8];
    const float* q_ba = (const float*)d_in[9];
    const float* q_bb = (const float*)d_in[10];
    const float* k_wa = (const float*)d_in[11];
    const float* k_wb = (const float*)d_in[12];
    const float* k_ba = (const float*)d_in[13];
    const float* k_bb = (const float*)d_in[14];
    const float* v_wa = (const float*)d_in[15];
    const float* v_wb = (const float*)d_in[16];
    const float* v_ba = (const float*)d_in[17];
    const float* v_bb = (const float*)d_in[18];
    const float* o_wa = (const float*)d_in[19];
    const float* o_wb = (const float*)d_in[20];
    const float* o_ba = (const float*)d_in[21];
    const float* o_bb = (const float*)d_in[22];

    float* W  = (float*)d_ws;
    float* qa = W;
    float* qb = W + 1*(size_t)BSE;
    float* ka = W + 2*(size_t)BSE;
    float* kb = W + 3*(size_t)BSE;
    float* va = W + 4*(size_t)BSE;
    float* vb = W + 5*(size_t)BSE;
    float* ao = W + 6*(size_t)BSE;
    float* bo = W + 7*(size_t)BSE;

    float* out_a = (float*)d_out;
    float* out_b = out_a + (size_t)BSE;

    const dim3 gg(EMB/64, (BATCH*SEQ)/64);   // (16, 32)

    qc_gemm<<<gg, 256, 0, stream>>>(x_q_a,  x_q_b,  q_wa, q_wb, q_ba, q_bb, theta, qa, qb);
    qc_gemm<<<gg, 256, 0, stream>>>(x_kv_a, x_kv_b, k_wa, k_wb, k_ba, k_bb, theta, ka, kb);
    qc_gemm<<<gg, 256, 0, stream>>>(x_kv_a, x_kv_b, v_wa, v_wb, v_ba, v_bb, theta, va, vb);

    rope_kernel<<<dim3((BATCH*SEQ*NH*32)/256, 4), 256, 0, stream>>>(qa, qb, ka, kb);

    attn_kernel<<<BATCH*NH*(SEQ/4), 256, 0, stream>>>(qa, qb, ka, kb, va, vb,
                                                      thetas_h, ao, bo);

    qc_gemm<<<gg, 256, 0, stream>>>(ao, bo, o_wa, o_wb, o_ba, o_bb, theta, out_a, out_b);
}

// Round 3
// 870.152 us; speedup vs baseline: 1.8756x; 1.8756x over previous
//
#include <hip/hip_runtime.h>
#include <math.h>
#include <stdint.h>

#define BATCH 2
#define SEQ   1024
#define EMB   1024
#define NH    16
#define DH    64
#define BSE   (BATCH*SEQ*EMB)   /* 2097152 elements per (B,S,E) tensor */
#define MROWS (BATCH*SEQ)       /* 2048 */

typedef unsigned short u16;
typedef __attribute__((ext_vector_type(8))) short short8;
typedef __attribute__((ext_vector_type(4))) float f32x4;

__device__ __forceinline__ float bf2f(u16 u) {
    return __uint_as_float(((unsigned int)u) << 16);
}
__device__ __forceinline__ u16 f2bf(float f) {
    unsigned int x = __float_as_uint(f);
    x += 0x7FFFu + ((x >> 16) & 1u);   // round-to-nearest-even
    return (u16)(x >> 16);
}

__device__ __forceinline__ void async_copy16(const void* g, void* l) {
    __builtin_amdgcn_global_load_lds(
        (const __attribute__((address_space(1))) unsigned int*)g,
        (__attribute__((address_space(3))) unsigned int*)l,
        16, 0, 0);
}

// ---------------------------------------------------------------------------
// Pack: fp32 -> bf16 elementwise, 16 tensors in one launch (blockIdx.y=entry).
// scaled entries multiply by j2 = sin(2*theta)-1 first.
// ---------------------------------------------------------------------------
struct PackArgs {
    const float* src[16];
    u16*         dst[16];
    int          n[16];
    int          scaled[16];
};

__global__ __launch_bounds__(256) void pack_kernel(PackArgs pa, const float* __restrict__ theta)
{
    const int e = blockIdx.y;
    const int i = (blockIdx.x * 256 + threadIdx.x) * 4;
    if (i >= pa.n[e]) return;
    float sc = 1.0f;
    if (pa.scaled[e]) sc = sinf(2.0f * theta[0]) - 1.0f;
    float4 v = *(const float4*)(pa.src[e] + i);
    u16* d = pa.dst[e] + i;
    ushort4 o;
    o.x = f2bf(v.x * sc); o.y = f2bf(v.y * sc);
    o.z = f2bf(v.z * sc); o.w = f2bf(v.w * sc);
    *(ushort4*)d = o;
}

// ---------------------------------------------------------------------------
// MFMA bf16 GEMM with virtual K-concat (K=2048) and N-segments of 1024.
//   C[m][n(seg,c)] = sum_{k<1024} A1[m][k]*Blo[seg][c][k]
//                  + sum_{k<1024} A2[m][k]*Bhi[seg][c][k]  + bias[seg][c]
// A1/A2, B* are row-major [*][1024] bf16. dst[seg] is [2048][1024]
// (bf16 if !OUT_F32 else fp32). 128x128 tile, BK=32, 4 waves, 16x16x32 MFMA.
// ---------------------------------------------------------------------------
struct GemmArgs {
    const u16*   A1;
    const u16*   A2;
    const u16*   Blo[4];
    const u16*   Bhi[4];
    const float* bias[4];
    void*        dst[4];
};

template<int OUT_F32>
__global__ __launch_bounds__(256) void mfma_gemm(GemmArgs ga)
{
    __shared__ u16 sA[128][32];
    __shared__ u16 sB[128][32];

    const int t    = threadIdx.x;
    const int lane = t & 63;
    const int w    = t >> 6;
    const int wx   = w & 1;
    const int wy   = w >> 1;
    const int n0   = blockIdx.x * 128;
    const int m0   = blockIdx.y * 128;
    const int seg  = n0 >> 10;
    const int nloc = n0 & 1023;

    const int srow = t >> 2;          // staging row within 64-row round
    const int sb   = (t & 3) * 16;    // staging byte offset within 64-B row

    f32x4 acc[4][4] = {};

    const char* A1 = (const char*)ga.A1;
    const char* A2 = (const char*)ga.A2;
    const char* Bl = (const char*)ga.Blo[seg];
    const char* Bh = (const char*)ga.Bhi[seg];

    const int frow = lane & 15;
    const int quad = lane >> 4;

    for (int kt = 0; kt < 64; ++kt) {
        const char* As = (kt & 32) ? A2 : A1;
        const char* Bs = (kt & 32) ? Bh : Bl;
        const size_t kbyte = (size_t)(kt & 31) * 64;   // ((kt*32)%1024)*2 bytes

        __syncthreads();   // previous iteration's frag reads complete
        #pragma unroll
        for (int r = 0; r < 2; ++r) {
            const int row = r*64 + srow;
            const int ldsoff = (r*64 + w*16) * 64;     // wave-uniform base (bytes)
            async_copy16(As + (size_t)(m0 + row)*2048 + kbyte + sb,
                         (char*)&sA[0][0] + ldsoff);
            async_copy16(Bs + (size_t)(nloc + row)*2048 + kbyte + sb,
                         (char*)&sB[0][0] + ldsoff);
        }
        __syncthreads();   // drains vmcnt for global_load_lds

        short8 af[4], bfr[4];
        #pragma unroll
        for (int i = 0; i < 4; ++i)
            af[i] = *(const short8*)&sA[wy*64 + i*16 + frow][quad*8];
        #pragma unroll
        for (int j = 0; j < 4; ++j)
            bfr[j] = *(const short8*)&sB[wx*64 + j*16 + frow][quad*8];

        #pragma unroll
        for (int i = 0; i < 4; ++i)
            #pragma unroll
            for (int j = 0; j < 4; ++j)
                acc[i][j] = __builtin_amdgcn_mfma_f32_16x16x32_bf16(
                                af[i], bfr[j], acc[i][j], 0, 0, 0);
    }

    // ---- epilogue: C/D layout col=lane&15, row=quad*4+reg ----
    const float* bias = ga.bias[seg];
    #pragma unroll
    for (int j = 0; j < 4; ++j) {
        const int c = nloc + wx*64 + j*16 + frow;   // col within this segment's 1024
        const float bv = bias[c];
        #pragma unroll
        for (int i = 0; i < 4; ++i) {
            #pragma unroll
            for (int reg = 0; reg < 4; ++reg) {
                const int m = m0 + wy*64 + i*16 + quad*4 + reg;
                const float val = acc[i][j][reg] + bv;
                if (OUT_F32) {
                    ((float*)ga.dst[seg])[(size_t)m*1024 + c] = val;
                } else {
                    ((u16*)ga.dst[seg])[(size_t)m*1024 + c] = f2bf(val);
                }
            }
        }
    }
}

// ---------------------------------------------------------------------------
// RoPE, in place on (B,S,E) bf16; pair (d, d+32) within each head.
// grid = (B*S*H*32/256, 4 tensors)
// ---------------------------------------------------------------------------
__global__ __launch_bounds__(256) void rope_kernel(
    u16* qa, u16* qb, u16* ka, u16* kb)
{
    u16* p;
    switch (blockIdx.y) {
        case 0:  p = qa; break;
        case 1:  p = qb; break;
        case 2:  p = ka; break;
        default: p = kb; break;
    }
    const int i   = blockIdx.x * 256 + threadIdx.x; // 0 .. B*S*H*32-1
    const int d   = i & 31;
    const int hh  = (i >> 5) & (NH - 1);
    const int row = i >> 9;            // b*S + s
    const int s   = row & (SEQ - 1);
    const size_t base = (size_t)row * EMB + hh * DH;

    float x1 = bf2f(p[base + d]);
    float x2 = bf2f(p[base + d + 32]);
    const float invf = expf(-(float)d * (9.210340371976184f / 32.0f)); // 10000^(-d/32)
    const float ang  = (float)s * invf;
    float sn, cs;
    sincosf(ang, &sn, &cs);
    p[base + d]      = f2bf(x1 * cs - x2 * sn);
    p[base + d + 32] = f2bf(x2 * cs + x1 * sn);
}

// ---------------------------------------------------------------------------
// Flash-style causal attention, bf16 I/O, fp32 compute (same as round-2).
// ---------------------------------------------------------------------------
__global__ __launch_bounds__(256) void attn_kernel(
    const u16* __restrict__ qa, const u16* __restrict__ qb,
    const u16* __restrict__ ka, const u16* __restrict__ kb,
    const u16* __restrict__ va, const u16* __restrict__ vb,
    const float* __restrict__ thetas,
    u16* __restrict__ oa, u16* __restrict__ ob)
{
    __shared__ float sA[64][66];
    __shared__ float sB[64][66];
    __shared__ float sQa[4][64];
    __shared__ float sQb[4][64];
    __shared__ float sP[4][64];

    const int t   = threadIdx.x;
    const int w   = t >> 6;
    const int L   = t & 63;
    const int bid = blockIdx.x;
    const int qt  = bid & (SEQ/4 - 1);
    const int bh  = bid / (SEQ/4);
    const int h   = bh & (NH - 1);
    const int b   = bh >> 4;
    const int q   = qt * 4 + w;

    const size_t rowQ = (size_t)(b*SEQ + q) * EMB + h * DH;
    sQa[w][L] = bf2f(qa[rowQ + L]);
    sQb[w][L] = bf2f(qb[rowQ + L]);
    __syncthreads();

    const float j2h = sinf(2.0f * thetas[h]) - 1.0f;

    float m_run = -1e30f, l_run = 0.0f;
    float acc_a = 0.0f, acc_b = 0.0f;

    const int lr = t >> 2;
    const int d0 = (t & 3) << 4;
    const int nt = ((qt*4 + 3) >> 6) + 1;

    for (int kt = 0; kt < nt; ++kt) {
        const size_t gbase = (size_t)(b*SEQ + kt*64 + lr) * EMB + h * DH + d0;

        __syncthreads();
        #pragma unroll
        for (int u = 0; u < 16; u += 4) {
            ushort4 uA = *(const ushort4*)(ka + gbase + u);
            ushort4 uB = *(const ushort4*)(kb + gbase + u);
            const int d = d0 + u;
            sA[lr][d+0] = bf2f(uA.x); sA[lr][d+1] = bf2f(uA.y);
            sA[lr][d+2] = bf2f(uA.z); sA[lr][d+3] = bf2f(uA.w);
            sB[lr][d+0] = bf2f(uB.x); sB[lr][d+1] = bf2f(uB.y);
            sB[lr][d+2] = bf2f(uB.z); sB[lr][d+3] = bf2f(uB.w);
        }
        __syncthreads();

        float s_aa = 0.f, s_bb = 0.f, s_ab = 0.f, s_ba = 0.f;
        #pragma unroll 8
        for (int d = 0; d < 64; ++d) {
            const float qra = sQa[w][d], qrb = sQb[w][d];
            const float kva = sA[L][d],  kvb = sB[L][d];
            s_aa += qra * kva;
            s_bb += qrb * kvb;
            s_ab += qra * kvb;
            s_ba += qrb * kva;
        }
        const float s_a = s_aa + j2h * s_bb;
        const float s_b = s_ab + s_ba;
        float mag = sqrtf(s_a*s_a + s_b*s_b + 1e-8f) * 0.125f;
        const int k = kt*64 + L;
        if (k > q) mag = -1e9f;

        float tmax = mag;
        #pragma unroll
        for (int off = 32; off >= 1; off >>= 1)
            tmax = fmaxf(tmax, __shfl_xor(tmax, off, 64));
        const float m_new = fmaxf(m_run, tmax);
        const float p = expf(mag - m_new);
        float psum = p;
        #pragma unroll
        for (int off = 32; off >= 1; off >>= 1)
            psum += __shfl_xor(psum, off, 64);
        const float alpha = expf(m_run - m_new);
        l_run = l_run * alpha + psum;
        m_run = m_new;
        acc_a *= alpha;
        acc_b *= alpha;
        sP[w][L] = p;

        __syncthreads();
        #pragma unroll
        for (int u = 0; u < 16; u += 4) {
            ushort4 uA = *(const ushort4*)(va + gbase + u);
            ushort4 uB = *(const ushort4*)(vb + gbase + u);
            const int d = d0 + u;
            sA[lr][d+0] = bf2f(uA.x); sA[lr][d+1] = bf2f(uA.y);
            sA[lr][d+2] = bf2f(uA.z); sA[lr][d+3] = bf2f(uA.w);
            sB[lr][d+0] = bf2f(uB.x); sB[lr][d+1] = bf2f(uB.y);
            sB[lr][d+2] = bf2f(uB.z); sB[lr][d+3] = bf2f(uB.w);
        }
        __syncthreads();

        #pragma unroll 8
        for (int kk = 0; kk < 64; ++kk) {
            const float pk = sP[w][kk];
            acc_a += pk * sA[kk][L];
            acc_b += pk * sB[kk][L];
        }
    }

    const float inv_l = 1.0f / l_run;
    oa[rowQ + L] = f2bf(acc_a * inv_l);
    ob[rowQ + L] = f2bf(acc_b * inv_l);
}

// ---------------------------------------------------------------------------
extern "C" void kernel_launch(void* const* d_in, const int* in_sizes, int n_in,
                              void* d_out, int out_size, void* d_ws, size_t ws_size,
                              hipStream_t stream)
{
    const float* x_q_a  = (const float*)d_in[0];
    const float* x_q_b  = (const float*)d_in[1];
    const float* x_kv_a = (const float*)d_in[2];
    const float* x_kv_b = (const float*)d_in[3];
    /* d_in[4] = mask (int32 tril) -- causal handled analytically */
    const float* theta    = (const float*)d_in[5];
    const float* thetas_h = (const float*)d_in[6];
    const float* q_wa = (const float*)d_in[7];
    const float* q_wb = (const float*)d_in[8];
    const float* q_ba = (const float*)d_in[9];
    const float* q_bb = (const float*)d_in[10];
    const float* k_wa = (const float*)d_in[11];
    const float* k_wb = (const float*)d_in[12];
    const float* k_ba = (const float*)d_in[13];
    const float* k_bb = (const float*)d_in[14];
    const float* v_wa = (const float*)d_in[15];
    const float* v_wb = (const float*)d_in[16];
    const float* v_ba = (const float*)d_in[17];
    const float* v_bb = (const float*)d_in[18];
    const float* o_wa = (const float*)d_in[19];
    const float* o_wb = (const float*)d_in[20];
    const float* o_ba = (const float*)d_in[21];
    const float* o_bb = (const float*)d_in[22];

    // ---- workspace layout (u16 units), 64 MB total ----
    u16* W = (u16*)d_ws;
    const size_t XN = (size_t)BSE;        // 2M elems per x tensor
    const size_t WN = (size_t)EMB*EMB;    // 1M elems per weight
    u16* xq_a16  = W;
    u16* xq_b16  = W + XN;
    u16* xkv_a16 = W + 2*XN;
    u16* xkv_b16 = W + 3*XN;
    u16* wbase   = W + 4*XN;              // 8M
    u16* q_wa16  = wbase;
    u16* q_wb16  = wbase + WN;
    u16* k_wa16  = wbase + 2*WN;
    u16* k_wb16  = wbase + 3*WN;
    u16* v_wa16  = wbase + 4*WN;
    u16* v_wb16  = wbase + 5*WN;
    u16* o_wa16  = wbase + 6*WN;
    u16* o_wb16  = wbase + 7*WN;
    u16* q_wbs16 = wbase + 8*WN;
    u16* k_wbs16 = wbase + 9*WN;
    u16* v_wbs16 = wbase + 10*WN;
    u16* o_wbs16 = wbase + 11*WN;
    u16* qkv     = wbase + 12*WN;         // 20M
    u16* qa16 = qkv;
    u16* qb16 = qkv + XN;
    u16* ka16 = qkv + 2*XN;
    u16* kb16 = qkv + 3*XN;
    u16* va16 = qkv + 4*XN;
    u16* vb16 = qkv + 5*XN;
    u16* ao16 = xq_a16;                   // alias: xq region free after GEMM1
    u16* bo16 = xq_b16;

    float* out_a = (float*)d_out;
    float* out_b = out_a + (size_t)BSE;

    // ---- 1. pack everything to bf16 ----
    PackArgs pa;
    const float* psrc[16] = { x_q_a, x_q_b, x_kv_a, x_kv_b,
                              q_wa, q_wb, k_wa, k_wb, v_wa, v_wb, o_wa, o_wb,
                              q_wb, k_wb, v_wb, o_wb };
    u16* pdst[16] = { xq_a16, xq_b16, xkv_a16, xkv_b16,
                      q_wa16, q_wb16, k_wa16, k_wb16, v_wa16, v_wb16, o_wa16, o_wb16,
                      q_wbs16, k_wbs16, v_wbs16, o_wbs16 };
    for (int e = 0; e < 16; ++e) {
        pa.src[e] = psrc[e];
        pa.dst[e] = pdst[e];
        pa.n[e]   = (e < 4) ? (int)XN : (int)WN;
        pa.scaled[e] = (e >= 12) ? 1 : 0;
    }
    pack_kernel<<<dim3(XN/(256*4), 16), 256, 0, stream>>>(pa, theta);

    // ---- 2. QKV projections via MFMA GEMMs ----
    GemmArgs g1;
    g1.A1 = xq_a16; g1.A2 = xq_b16;
    g1.Blo[0] = q_wa16;  g1.Bhi[0] = q_wbs16; g1.bias[0] = q_ba; g1.dst[0] = qa16;
    g1.Blo[1] = q_wb16;  g1.Bhi[1] = q_wa16;  g1.bias[1] = q_bb; g1.dst[1] = qb16;
    g1.Blo[2] = q_wa16;  g1.Bhi[2] = q_wa16;  g1.bias[2] = q_ba; g1.dst[2] = qa16;
    g1.Blo[3] = q_wa16;  g1.Bhi[3] = q_wa16;  g1.bias[3] = q_ba; g1.dst[3] = qa16;
    mfma_gemm<0><<<dim3(16, MROWS/128), 256, 0, stream>>>(g1);

    GemmArgs g2;
    g2.A1 = xkv_a16; g2.A2 = xkv_b16;
    g2.Blo[0] = k_wa16; g2.Bhi[0] = k_wbs16; g2.bias[0] = k_ba; g2.dst[0] = ka16;
    g2.Blo[1] = k_wb16; g2.Bhi[1] = k_wa16;  g2.bias[1] = k_bb; g2.dst[1] = kb16;
    g2.Blo[2] = v_wa16; g2.Bhi[2] = v_wbs16; g2.bias[2] = v_ba; g2.dst[2] = va16;
    g2.Blo[3] = v_wb16; g2.Bhi[3] = v_wa16;  g2.bias[3] = v_bb; g2.dst[3] = vb16;
    mfma_gemm<0><<<dim3(32, MROWS/128), 256, 0, stream>>>(g2);

    // ---- 3. RoPE ----
    rope_kernel<<<dim3((BATCH*SEQ*NH*32)/256, 4), 256, 0, stream>>>(qa16, qb16, ka16, kb16);

    // ---- 4. attention ----
    attn_kernel<<<BATCH*NH*(SEQ/4), 256, 0, stream>>>(qa16, qb16, ka16, kb16,
                                                      va16, vb16, thetas_h, ao16, bo16);

    // ---- 5. output projection (fp32 out) ----
    GemmArgs g3;
    g3.A1 = ao16; g3.A2 = bo16;
    g3.Blo[0] = o_wa16; g3.Bhi[0] = o_wbs16; g3.bias[0] = o_ba; g3.dst[0] = out_a;
    g3.Blo[1] = o_wb16; g3.Bhi[1] = o_wa16;  g3.bias[1] = o_bb; g3.dst[1] = out_b;
    g3.Blo[2] = o_wa16; g3.Bhi[2] = o_wa16;  g3.bias[2] = o_ba; g3.dst[2] = out_a;
    g3.Blo[3] = o_wa16; g3.Bhi[3] = o_wa16;  g3.bias[3] = o_ba; g3.dst[3] = out_a;
    mfma_gemm<1><<<dim3(16, MROWS/128), 256, 0, stream>>>(g3);
}

// Round 4
// 355.379 us; speedup vs baseline: 4.5925x; 2.4485x over previous
//
#include <hip/hip_runtime.h>
#include <math.h>
#include <stdint.h>

#define BATCH 2
#define SEQ   1024
#define EMB   1024
#define NH    16
#define DH    64
#define BSE   (BATCH*SEQ*EMB)   /* 2097152 elements per (B,S,E) tensor */
#define MROWS (BATCH*SEQ)       /* 2048 */

typedef unsigned short u16;
typedef __attribute__((ext_vector_type(8))) short short8;
typedef __attribute__((ext_vector_type(4))) float f32x4;

__device__ __forceinline__ float bf2f(u16 u) {
    return __uint_as_float(((unsigned int)u) << 16);
}
__device__ __forceinline__ u16 f2bf(float f) {
    unsigned int x = __float_as_uint(f);
    x += 0x7FFFu + ((x >> 16) & 1u);   // round-to-nearest-even
    return (u16)(x >> 16);
}

__device__ __forceinline__ void async_copy16(const void* g, void* l) {
    __builtin_amdgcn_global_load_lds(
        (const __attribute__((address_space(1))) unsigned int*)g,
        (__attribute__((address_space(3))) unsigned int*)l,
        16, 0, 0);
}

// ---------------------------------------------------------------------------
// Pack: fp32 -> bf16 elementwise, 16 tensors in one launch (blockIdx.y=entry).
// scaled entries multiply by j2 = sin(2*theta)-1 first.
// ---------------------------------------------------------------------------
struct PackArgs {
    const float* src[16];
    u16*         dst[16];
    int          n[16];
    int          scaled[16];
};

__global__ __launch_bounds__(256) void pack_kernel(PackArgs pa, const float* __restrict__ theta)
{
    const int e = blockIdx.y;
    const int i = (blockIdx.x * 256 + threadIdx.x) * 4;
    if (i >= pa.n[e]) return;
    float sc = 1.0f;
    if (pa.scaled[e]) sc = sinf(2.0f * theta[0]) - 1.0f;
    float4 v = *(const float4*)(pa.src[e] + i);
    u16* d = pa.dst[e] + i;
    ushort4 o;
    o.x = f2bf(v.x * sc); o.y = f2bf(v.y * sc);
    o.z = f2bf(v.z * sc); o.w = f2bf(v.w * sc);
    *(ushort4*)d = o;
}

// ---------------------------------------------------------------------------
// MFMA bf16 GEMM with virtual K-concat (K=2048) and N-segments of 1024.
// mode per segment: 0 = bf16 [m][c] store, 1 = fp32 [m][c] store,
//                   2 = bf16 transposed store dst[b][c][s]  (for V^T)
// ---------------------------------------------------------------------------
struct GemmArgs {
    const u16*   A1;
    const u16*   A2;
    const u16*   Blo[4];
    const u16*   Bhi[4];
    const float* bias[4];
    void*        dst[4];
    int          mode[4];
};

__global__ __launch_bounds__(256) void mfma_gemm(GemmArgs ga)
{
    __shared__ u16 sA[128][32];
    __shared__ u16 sB[128][32];

    const int t    = threadIdx.x;
    const int lane = t & 63;
    const int w    = t >> 6;
    const int wx   = w & 1;
    const int wy   = w >> 1;
    const int n0   = blockIdx.x * 128;
    const int m0   = blockIdx.y * 128;
    const int seg  = n0 >> 10;
    const int nloc = n0 & 1023;

    const int srow = t >> 2;          // staging row within 64-row round
    const int sb   = (t & 3) * 16;    // staging byte offset within 64-B row

    f32x4 acc[4][4] = {};

    const char* A1 = (const char*)ga.A1;
    const char* A2 = (const char*)ga.A2;
    const char* Bl = (const char*)ga.Blo[seg];
    const char* Bh = (const char*)ga.Bhi[seg];

    const int frow = lane & 15;
    const int quad = lane >> 4;

    for (int kt = 0; kt < 64; ++kt) {
        const char* As = (kt & 32) ? A2 : A1;
        const char* Bs = (kt & 32) ? Bh : Bl;
        const size_t kbyte = (size_t)(kt & 31) * 64;

        __syncthreads();
        #pragma unroll
        for (int r = 0; r < 2; ++r) {
            const int row = r*64 + srow;
            const int ldsoff = (r*64 + w*16) * 64;
            async_copy16(As + (size_t)(m0 + row)*2048 + kbyte + sb,
                         (char*)&sA[0][0] + ldsoff);
            async_copy16(Bs + (size_t)(nloc + row)*2048 + kbyte + sb,
                         (char*)&sB[0][0] + ldsoff);
        }
        __syncthreads();

        short8 af[4], bfr[4];
        #pragma unroll
        for (int i = 0; i < 4; ++i)
            af[i] = *(const short8*)&sA[wy*64 + i*16 + frow][quad*8];
        #pragma unroll
        for (int j = 0; j < 4; ++j)
            bfr[j] = *(const short8*)&sB[wx*64 + j*16 + frow][quad*8];

        #pragma unroll
        for (int i = 0; i < 4; ++i)
            #pragma unroll
            for (int j = 0; j < 4; ++j)
                acc[i][j] = __builtin_amdgcn_mfma_f32_16x16x32_bf16(
                                af[i], bfr[j], acc[i][j], 0, 0, 0);
    }

    // ---- epilogue: C/D layout col=lane&15, row=quad*4+reg ----
    const float* bias = ga.bias[seg];
    const int mode = ga.mode[seg];
    #pragma unroll
    for (int j = 0; j < 4; ++j) {
        const int c = nloc + wx*64 + j*16 + frow;
        const float bv = bias[c];
        #pragma unroll
        for (int i = 0; i < 4; ++i) {
            #pragma unroll
            for (int reg = 0; reg < 4; ++reg) {
                const int m = m0 + wy*64 + i*16 + quad*4 + reg;
                const float val = acc[i][j][reg] + bv;
                if (mode == 1) {
                    ((float*)ga.dst[seg])[(size_t)m*1024 + c] = val;
                } else if (mode == 2) {
                    // V^T: [b][c][s], b = m>>10, s = m&1023
                    ((u16*)ga.dst[seg])[((size_t)(m >> 10) << 20) + (size_t)c*1024 + (m & 1023)] = f2bf(val);
                } else {
                    ((u16*)ga.dst[seg])[(size_t)m*1024 + c] = f2bf(val);
                }
            }
        }
    }
}

// ---------------------------------------------------------------------------
// RoPE, in place on (B,S,E) bf16; pair (d, d+32) within each head.
// ---------------------------------------------------------------------------
__global__ __launch_bounds__(256) void rope_kernel(
    u16* qa, u16* qb, u16* ka, u16* kb)
{
    u16* p;
    switch (blockIdx.y) {
        case 0:  p = qa; break;
        case 1:  p = qb; break;
        case 2:  p = ka; break;
        default: p = kb; break;
    }
    const int i   = blockIdx.x * 256 + threadIdx.x;
    const int d   = i & 31;
    const int hh  = (i >> 5) & (NH - 1);
    const int row = i >> 9;
    const int s   = row & (SEQ - 1);
    const size_t base = (size_t)row * EMB + hh * DH;

    float x1 = bf2f(p[base + d]);
    float x2 = bf2f(p[base + d + 32]);
    const float invf = expf(-(float)d * (9.210340371976184f / 32.0f));
    const float ang  = (float)s * invf;
    float sn, cs;
    sincosf(ang, &sn, &cs);
    p[base + d]      = f2bf(x1 * cs - x2 * sn);
    p[base + d + 32] = f2bf(x2 * cs + x1 * sn);
}

// ---------------------------------------------------------------------------
// MFMA flash attention. Block = 4 waves; one (b,h), 64 q-rows (16 per wave).
// K-tiles of 64 keys. K/V staged via global_load_lds w/ XOR chunk swizzle.
//   s_a = [qa | j2h*qb] . [ka|kb]^T ; s_b = [qa|qb] . [kb|ka]^T  (K=128)
//   mag = sqrt(s_a^2+s_b^2+1e-8)/8 ; causal ; online softmax ; O += P.V
// V supplied transposed: vt[b][c=h*64+d][s].
// Block mapping: paired qt so co-resident blocks have ~constant total work.
// ---------------------------------------------------------------------------
__global__ __launch_bounds__(256) void attn_mfma(
    const u16* __restrict__ qa, const u16* __restrict__ qb,
    const u16* __restrict__ ka, const u16* __restrict__ kb,
    const u16* __restrict__ vat, const u16* __restrict__ vbt,
    const float* __restrict__ thetas,
    u16* __restrict__ oa, u16* __restrict__ ob)
{
    __shared__ u16 sKa[64][64];
    __shared__ u16 sKb[64][64];
    __shared__ u16 sVa[64][64];
    __shared__ u16 sVb[64][64];
    __shared__ u16 sP[4][16][72];   // wave-private P, stride 72 hw (16B-aligned rows)

    const int t    = threadIdx.x;
    const int lane = t & 63;
    const int w    = t >> 6;
    const int L15  = lane & 15;
    const int quad = lane >> 4;

    // work-balanced mapping: bid<256 -> qt=15..8 ; bid>=256 -> qt=0..7
    const int bid  = blockIdx.x;
    const int aa   = (bid >> 5) & 7;
    const int qt   = (bid >> 8) ? aa : (15 - aa);
    const int bh   = bid & 31;
    const int h    = bh & 15;
    const int b    = bh >> 4;

    const float j2h = sinf(2.0f * thetas[h]) - 1.0f;

    // ---- Q fragments (A-operand: m=lane&15, k=quad*8+j), 2 slices of 32 ----
    const int   qrow  = qt*64 + w*16 + L15;
    const size_t qbase = (size_t)(b*SEQ + qrow) * EMB + h*DH;
    short8 fqa[2], fqb[2], fjqb[2];
    fqa[0] = *(const short8*)(qa + qbase + quad*8);
    fqa[1] = *(const short8*)(qa + qbase + 32 + quad*8);
    fqb[0] = *(const short8*)(qb + qbase + quad*8);
    fqb[1] = *(const short8*)(qb + qbase + 32 + quad*8);
    #pragma unroll
    for (int s2 = 0; s2 < 2; ++s2) {
        short8 src = fqb[s2], dst;
        #pragma unroll
        for (int j = 0; j < 8; ++j)
            dst[j] = (short)f2bf(bf2f((u16)src[j]) * j2h);
        fjqb[s2] = dst;
    }

    f32x4 acc_a[4] = {};   // O_a: [n-dim-subtile], C layout
    f32x4 acc_b[4] = {};
    float m_run[4] = {-1e30f, -1e30f, -1e30f, -1e30f};
    float l_run[4] = {0.f, 0.f, 0.f, 0.f};

    // staging: each wave stages 16 rows/tensor, 2 instrs each; 8 rows/instr.
    // lane: subrow = lane>>3, chunk slot cs = lane&7, global chunk g = cs^subrow.
    const int subrow = lane >> 3;
    const int g      = (lane & 7) ^ subrow;
    const int swz    = L15 & 7;        // read-side swizzle key

    for (int kt = 0; kt <= qt; ++kt) {
        __syncthreads();
        #pragma unroll
        for (int i = 0; i < 2; ++i) {
            const int row = w*16 + i*8 + subrow;         // 0..63
            const int ldsoff = (w*16 + i*8) * 128;       // wave-uniform (bytes)
            const size_t ktok = (size_t)(b*SEQ + kt*64 + row);
            async_copy16((const char*)ka + ktok*2048 + h*128 + g*16,
                         (char*)&sKa[0][0] + ldsoff);
            async_copy16((const char*)kb + ktok*2048 + h*128 + g*16,
                         (char*)&sKb[0][0] + ldsoff);
            const size_t vrow = (size_t)b*1048576 + (size_t)(h*64 + row)*1024 + kt*64;
            async_copy16((const char*)vat + vrow*2 + g*16,
                         (char*)&sVa[0][0] + ldsoff);
            async_copy16((const char*)vbt + vrow*2 + g*16,
                         (char*)&sVb[0][0] + ldsoff);
        }
        __syncthreads();

        // ---- scores ----
        f32x4 sa[4] = {}, sb[4] = {};
        #pragma unroll
        for (int n = 0; n < 4; ++n) {
            const u16* rKa = &sKa[n*16 + L15][0];
            const u16* rKb = &sKb[n*16 + L15][0];
            short8 ka0 = *(const short8*)(rKa + (( quad      ^ swz) << 3));
            short8 ka1 = *(const short8*)(rKa + (((4 + quad) ^ swz) << 3));
            short8 kb0 = *(const short8*)(rKb + (( quad      ^ swz) << 3));
            short8 kb1 = *(const short8*)(rKb + (((4 + quad) ^ swz) << 3));
            sa[n] = __builtin_amdgcn_mfma_f32_16x16x32_bf16(fqa[0],  ka0, sa[n], 0, 0, 0);
            sa[n] = __builtin_amdgcn_mfma_f32_16x16x32_bf16(fqa[1],  ka1, sa[n], 0, 0, 0);
            sa[n] = __builtin_amdgcn_mfma_f32_16x16x32_bf16(fjqb[0], kb0, sa[n], 0, 0, 0);
            sa[n] = __builtin_amdgcn_mfma_f32_16x16x32_bf16(fjqb[1], kb1, sa[n], 0, 0, 0);
            sb[n] = __builtin_amdgcn_mfma_f32_16x16x32_bf16(fqa[0],  kb0, sb[n], 0, 0, 0);
            sb[n] = __builtin_amdgcn_mfma_f32_16x16x32_bf16(fqa[1],  kb1, sb[n], 0, 0, 0);
            sb[n] = __builtin_amdgcn_mfma_f32_16x16x32_bf16(fqb[0],  ka0, sb[n], 0, 0, 0);
            sb[n] = __builtin_amdgcn_mfma_f32_16x16x32_bf16(fqb[1],  ka1, sb[n], 0, 0, 0);
        }

        // ---- magnitude + causal mask (element row=quad*4+reg, col=n*16+L15) ----
        float mag[4][4];
        #pragma unroll
        for (int n = 0; n < 4; ++n)
            #pragma unroll
            for (int r = 0; r < 4; ++r) {
                const float A = sa[n][r], B = sb[n][r];
                mag[n][r] = sqrtf(A*A + B*B + 1e-8f) * 0.125f;
            }
        if (kt == qt) {
            #pragma unroll
            for (int n = 0; n < 4; ++n)
                #pragma unroll
                for (int r = 0; r < 4; ++r)
                    if (n*16 + L15 > w*16 + quad*4 + r) mag[n][r] = -1e9f;
        }

        // ---- online softmax (rows live across 16 lanes of a quad) ----
        float rmax[4], psum[4], alpha[4];
        #pragma unroll
        for (int r = 0; r < 4; ++r) {
            float mx = fmaxf(fmaxf(mag[0][r], mag[1][r]), fmaxf(mag[2][r], mag[3][r]));
            #pragma unroll
            for (int off = 8; off >= 1; off >>= 1)
                mx = fmaxf(mx, __shfl_xor(mx, off, 64));
            rmax[r] = mx;
        }
        float p[4][4];
        #pragma unroll
        for (int r = 0; r < 4; ++r) {
            const float m_new = fmaxf(m_run[r], rmax[r]);
            alpha[r] = expf(m_run[r] - m_new);
            m_run[r] = m_new;
            float ps = 0.f;
            #pragma unroll
            for (int n = 0; n < 4; ++n) {
                p[n][r] = expf(mag[n][r] - m_new);
                ps += p[n][r];
            }
            #pragma unroll
            for (int off = 8; off >= 1; off >>= 1)
                ps += __shfl_xor(ps, off, 64);
            psum[r] = ps;
            l_run[r] = l_run[r] * alpha[r] + psum[r];
        }
        #pragma unroll
        for (int n = 0; n < 4; ++n)
            #pragma unroll
            for (int r = 0; r < 4; ++r) {
                acc_a[n][r] *= alpha[r];
                acc_b[n][r] *= alpha[r];
            }

        // ---- P -> LDS (wave-private), re-enter as A-operand ----
        #pragma unroll
        for (int n = 0; n < 4; ++n)
            #pragma unroll
            for (int r = 0; r < 4; ++r)
                sP[w][quad*4 + r][n*16 + L15] = f2bf(p[n][r]);

        short8 pf0 = *(const short8*)&sP[w][L15][quad*8];        // keys 0..31
        short8 pf1 = *(const short8*)&sP[w][L15][32 + quad*8];   // keys 32..63

        // ---- PV ----
        #pragma unroll
        for (int n = 0; n < 4; ++n) {
            const u16* rVa = &sVa[n*16 + L15][0];
            const u16* rVb = &sVb[n*16 + L15][0];
            short8 va0 = *(const short8*)(rVa + (( quad      ^ swz) << 3));
            short8 va1 = *(const short8*)(rVa + (((4 + quad) ^ swz) << 3));
            short8 vb0 = *(const short8*)(rVb + (( quad      ^ swz) << 3));
            short8 vb1 = *(const short8*)(rVb + (((4 + quad) ^ swz) << 3));
            acc_a[n] = __builtin_amdgcn_mfma_f32_16x16x32_bf16(pf0, va0, acc_a[n], 0, 0, 0);
            acc_a[n] = __builtin_amdgcn_mfma_f32_16x16x32_bf16(pf1, va1, acc_a[n], 0, 0, 0);
            acc_b[n] = __builtin_amdgcn_mfma_f32_16x16x32_bf16(pf0, vb0, acc_b[n], 0, 0, 0);
            acc_b[n] = __builtin_amdgcn_mfma_f32_16x16x32_bf16(pf1, vb1, acc_b[n], 0, 0, 0);
        }
    }

    // ---- write out (C layout: row=quad*4+reg, col=n*16+L15) ----
    float inv[4];
    #pragma unroll
    for (int r = 0; r < 4; ++r) inv[r] = 1.0f / l_run[r];
    #pragma unroll
    for (int reg = 0; reg < 4; ++reg) {
        const size_t tok = (size_t)(b*SEQ + qt*64 + w*16 + quad*4 + reg);
        #pragma unroll
        for (int n = 0; n < 4; ++n) {
            const size_t idx = tok*EMB + h*DH + n*16 + L15;
            oa[idx] = f2bf(acc_a[n][reg] * inv[reg]);
            ob[idx] = f2bf(acc_b[n][reg] * inv[reg]);
        }
    }
}

// ---------------------------------------------------------------------------
extern "C" void kernel_launch(void* const* d_in, const int* in_sizes, int n_in,
                              void* d_out, int out_size, void* d_ws, size_t ws_size,
                              hipStream_t stream)
{
    const float* x_q_a  = (const float*)d_in[0];
    const float* x_q_b  = (const float*)d_in[1];
    const float* x_kv_a = (const float*)d_in[2];
    const float* x_kv_b = (const float*)d_in[3];
    const float* theta    = (const float*)d_in[5];
    const float* thetas_h = (const float*)d_in[6];
    const float* q_wa = (const float*)d_in[7];
    const float* q_wb = (const float*)d_in[8];
    const float* q_ba = (const float*)d_in[9];
    const float* q_bb = (const float*)d_in[10];
    const float* k_wa = (const float*)d_in[11];
    const float* k_wb = (const float*)d_in[12];
    const float* k_ba = (const float*)d_in[13];
    const float* k_bb = (const float*)d_in[14];
    const float* v_wa = (const float*)d_in[15];
    const float* v_wb = (const float*)d_in[16];
    const float* v_ba = (const float*)d_in[17];
    const float* v_bb = (const float*)d_in[18];
    const float* o_wa = (const float*)d_in[19];
    const float* o_wb = (const float*)d_in[20];
    const float* o_ba = (const float*)d_in[21];
    const float* o_bb = (const float*)d_in[22];

    u16* W = (u16*)d_ws;
    const size_t XN = (size_t)BSE;
    const size_t WN = (size_t)EMB*EMB;
    u16* xq_a16  = W;
    u16* xq_b16  = W + XN;
    u16* xkv_a16 = W + 2*XN;
    u16* xkv_b16 = W + 3*XN;
    u16* wbase   = W + 4*XN;
    u16* q_wa16  = wbase;
    u16* q_wb16  = wbase + WN;
    u16* k_wa16  = wbase + 2*WN;
    u16* k_wb16  = wbase + 3*WN;
    u16* v_wa16  = wbase + 4*WN;
    u16* v_wb16  = wbase + 5*WN;
    u16* o_wa16  = wbase + 6*WN;
    u16* o_wb16  = wbase + 7*WN;
    u16* q_wbs16 = wbase + 8*WN;
    u16* k_wbs16 = wbase + 9*WN;
    u16* v_wbs16 = wbase + 10*WN;
    u16* o_wbs16 = wbase + 11*WN;
    u16* qkv     = wbase + 12*WN;
    u16* qa16 = qkv;
    u16* qb16 = qkv + XN;
    u16* ka16 = qkv + 2*XN;
    u16* kb16 = qkv + 3*XN;
    u16* vat16 = qkv + 4*XN;   // transposed [b][c][s]
    u16* vbt16 = qkv + 5*XN;
    u16* ao16 = xq_a16;        // alias: xq region free after GEMM1
    u16* bo16 = xq_b16;

    float* out_a = (float*)d_out;
    float* out_b = out_a + (size_t)BSE;

    // ---- 1. pack to bf16 ----
    PackArgs pa;
    const float* psrc[16] = { x_q_a, x_q_b, x_kv_a, x_kv_b,
                              q_wa, q_wb, k_wa, k_wb, v_wa, v_wb, o_wa, o_wb,
                              q_wb, k_wb, v_wb, o_wb };
    u16* pdst[16] = { xq_a16, xq_b16, xkv_a16, xkv_b16,
                      q_wa16, q_wb16, k_wa16, k_wb16, v_wa16, v_wb16, o_wa16, o_wb16,
                      q_wbs16, k_wbs16, v_wbs16, o_wbs16 };
    for (int e = 0; e < 16; ++e) {
        pa.src[e] = psrc[e];
        pa.dst[e] = pdst[e];
        pa.n[e]   = (e < 4) ? (int)XN : (int)WN;
        pa.scaled[e] = (e >= 12) ? 1 : 0;
    }
    pack_kernel<<<dim3(XN/(256*4), 16), 256, 0, stream>>>(pa, theta);

    // ---- 2. projections ----
    GemmArgs g1;
    g1.A1 = xq_a16; g1.A2 = xq_b16;
    g1.Blo[0] = q_wa16;  g1.Bhi[0] = q_wbs16; g1.bias[0] = q_ba; g1.dst[0] = qa16; g1.mode[0] = 0;
    g1.Blo[1] = q_wb16;  g1.Bhi[1] = q_wa16;  g1.bias[1] = q_bb; g1.dst[1] = qb16; g1.mode[1] = 0;
    g1.Blo[2] = q_wa16;  g1.Bhi[2] = q_wa16;  g1.bias[2] = q_ba; g1.dst[2] = qa16; g1.mode[2] = 0;
    g1.Blo[3] = q_wa16;  g1.Bhi[3] = q_wa16;  g1.bias[3] = q_ba; g1.dst[3] = qa16; g1.mode[3] = 0;
    mfma_gemm<<<dim3(16, MROWS/128), 256, 0, stream>>>(g1);

    GemmArgs g2;
    g2.A1 = xkv_a16; g2.A2 = xkv_b16;
    g2.Blo[0] = k_wa16; g2.Bhi[0] = k_wbs16; g2.bias[0] = k_ba; g2.dst[0] = ka16;  g2.mode[0] = 0;
    g2.Blo[1] = k_wb16; g2.Bhi[1] = k_wa16;  g2.bias[1] = k_bb; g2.dst[1] = kb16;  g2.mode[1] = 0;
    g2.Blo[2] = v_wa16; g2.Bhi[2] = v_wbs16; g2.bias[2] = v_ba; g2.dst[2] = vat16; g2.mode[2] = 2;
    g2.Blo[3] = v_wb16; g2.Bhi[3] = v_wa16;  g2.bias[3] = v_bb; g2.dst[3] = vbt16; g2.mode[3] = 2;
    mfma_gemm<<<dim3(32, MROWS/128), 256, 0, stream>>>(g2);

    // ---- 3. RoPE (q/k only) ----
    rope_kernel<<<dim3((BATCH*SEQ*NH*32)/256, 4), 256, 0, stream>>>(qa16, qb16, ka16, kb16);

    // ---- 4. attention (MFMA flash) ----
    attn_mfma<<<BATCH*NH*(SEQ/64), 256, 0, stream>>>(qa16, qb16, ka16, kb16,
                                                     vat16, vbt16, thetas_h, ao16, bo16);

    // ---- 5. output projection (fp32 out) ----
    GemmArgs g3;
    g3.A1 = ao16; g3.A2 = bo16;
    g3.Blo[0] = o_wa16; g3.Bhi[0] = o_wbs16; g3.bias[0] = o_ba; g3.dst[0] = out_a; g3.mode[0] = 1;
    g3.Blo[1] = o_wb16; g3.Bhi[1] = o_wa16;  g3.bias[1] = o_bb; g3.dst[1] = out_b; g3.mode[1] = 1;
    g3.Blo[2] = o_wa16; g3.Bhi[2] = o_wa16;  g3.bias[2] = o_ba; g3.dst[2] = out_a; g3.mode[2] = 1;
    g3.Blo[3] = o_wa16; g3.Bhi[3] = o_wa16;  g3.bias[3] = o_ba; g3.dst[3] = out_a; g3.mode[3] = 1;
    mfma_gemm<<<dim3(16, MROWS/128), 256, 0, stream>>>(g3);
}

// Round 5
// 344.658 us; speedup vs baseline: 4.7354x; 1.0311x over previous
//
#include <hip/hip_runtime.h>
#include <math.h>
#include <stdint.h>

#define BATCH 2
#define SEQ   1024
#define EMB   1024
#define NH    16
#define DH    64
#define BSE   (BATCH*SEQ*EMB)   /* 2097152 elements per (B,S,E) tensor */
#define MROWS (BATCH*SEQ)       /* 2048 */

typedef unsigned short u16;
typedef __attribute__((ext_vector_type(8))) short short8;
typedef __attribute__((ext_vector_type(4))) float f32x4;

__device__ __forceinline__ float bf2f(u16 u) {
    return __uint_as_float(((unsigned int)u) << 16);
}
__device__ __forceinline__ u16 f2bf(float f) {
    unsigned int x = __float_as_uint(f);
    x += 0x7FFFu + ((x >> 16) & 1u);   // round-to-nearest-even
    return (u16)(x >> 16);
}

__device__ __forceinline__ void async_copy16(const void* g, void* l) {
    __builtin_amdgcn_global_load_lds(
        (const __attribute__((address_space(1))) unsigned int*)g,
        (__attribute__((address_space(3))) unsigned int*)l,
        16, 0, 0);
}

// ---------------------------------------------------------------------------
// Pack: fp32 -> bf16 elementwise, 16 tensors in one launch (blockIdx.y=entry).
// scaled entries multiply by j2 = sin(2*theta)-1 first.
// ---------------------------------------------------------------------------
struct PackArgs {
    const float* src[16];
    u16*         dst[16];
    int          n[16];
    int          scaled[16];
};

__global__ __launch_bounds__(256) void pack_kernel(PackArgs pa, const float* __restrict__ theta)
{
    const int e = blockIdx.y;
    const int i = (blockIdx.x * 256 + threadIdx.x) * 4;
    if (i >= pa.n[e]) return;
    float sc = 1.0f;
    if (pa.scaled[e]) sc = sinf(2.0f * theta[0]) - 1.0f;
    float4 v = *(const float4*)(pa.src[e] + i);
    u16* d = pa.dst[e] + i;
    ushort4 o;
    o.x = f2bf(v.x * sc); o.y = f2bf(v.y * sc);
    o.z = f2bf(v.z * sc); o.w = f2bf(v.w * sc);
    *(ushort4*)d = o;
}

// ---------------------------------------------------------------------------
// MFMA bf16 GEMM with virtual K-concat (K=2048), up to 8 N-segments of 1024.
//   C[m][c] = sum_k A1[m][k]*Blo[c][k] + A2[m][k]*Bhi[c][k] + bias[c]
// mode: 0 = bf16 [m][c] store, 1 = fp32 [m][c] store,
//       2 = bf16 transposed store dst[b][c][s]  (V^T),
//       3 = bf16 [m][c] store with fused RoPE (q/k heads, Dh=64)
// 128x128 tile, BK=32, 4 waves, 16x16x32 MFMA, global_load_lds width-16.
// ---------------------------------------------------------------------------
struct GemmArgs {
    const u16*   A1s[8];
    const u16*   A2s[8];
    const u16*   Blo[8];
    const u16*   Bhi[8];
    const float* bias[8];
    void*        dst[8];
    int          mode[8];
};

__global__ __launch_bounds__(256) void mfma_gemm(GemmArgs ga)
{
    __shared__ u16 sA[128][32];
    __shared__ u16 sB[128][32];

    const int t    = threadIdx.x;
    const int lane = t & 63;
    const int w    = t >> 6;
    const int wx   = w & 1;
    const int wy   = w >> 1;
    const int n0   = blockIdx.x * 128;
    const int m0   = blockIdx.y * 128;
    const int seg  = n0 >> 10;
    const int nloc = n0 & 1023;

    const int srow = t >> 2;          // staging row within 64-row round
    const int sb   = (t & 3) * 16;    // staging byte offset within 64-B row

    f32x4 acc[4][4] = {};

    const char* A1 = (const char*)ga.A1s[seg];
    const char* A2 = (const char*)ga.A2s[seg];
    const char* Bl = (const char*)ga.Blo[seg];
    const char* Bh = (const char*)ga.Bhi[seg];

    const int frow = lane & 15;
    const int quad = lane >> 4;

    for (int kt = 0; kt < 64; ++kt) {
        const char* As = (kt & 32) ? A2 : A1;
        const char* Bs = (kt & 32) ? Bh : Bl;
        const size_t kbyte = (size_t)(kt & 31) * 64;

        __syncthreads();
        #pragma unroll
        for (int r = 0; r < 2; ++r) {
            const int row = r*64 + srow;
            const int ldsoff = (r*64 + w*16) * 64;
            async_copy16(As + (size_t)(m0 + row)*2048 + kbyte + sb,
                         (char*)&sA[0][0] + ldsoff);
            async_copy16(Bs + (size_t)(nloc + row)*2048 + kbyte + sb,
                         (char*)&sB[0][0] + ldsoff);
        }
        __syncthreads();

        short8 af[4], bfr[4];
        #pragma unroll
        for (int i = 0; i < 4; ++i)
            af[i] = *(const short8*)&sA[wy*64 + i*16 + frow][quad*8];
        #pragma unroll
        for (int j = 0; j < 4; ++j)
            bfr[j] = *(const short8*)&sB[wx*64 + j*16 + frow][quad*8];

        #pragma unroll
        for (int i = 0; i < 4; ++i)
            #pragma unroll
            for (int j = 0; j < 4; ++j)
                acc[i][j] = __builtin_amdgcn_mfma_f32_16x16x32_bf16(
                                af[i], bfr[j], acc[i][j], 0, 0, 0);
    }

    // ---- epilogue: C/D layout col=lane&15, row=quad*4+reg ----
    const float* bias = ga.bias[seg];
    const int mode = ga.mode[seg];

    // bias (in place)
    #pragma unroll
    for (int j = 0; j < 4; ++j) {
        const int c = nloc + wx*64 + j*16 + frow;
        const float bv = bias[c];
        #pragma unroll
        for (int i = 0; i < 4; ++i)
            #pragma unroll
            for (int reg = 0; reg < 4; ++reg)
                acc[i][j][reg] += bv;
    }

    // fused RoPE: cols within head pair as (j, j+2) in the same thread.
    // head-local dim d = j*16+frow (head width 64, nloc+wx*64 is head-aligned).
    if (mode == 3) {
        #pragma unroll
        for (int jj = 0; jj < 2; ++jj) {
            const float invf = expf(-(float)(jj*16 + frow) * 0.28782313662425576f); // 10000^{-d/32}
            #pragma unroll
            for (int i = 0; i < 4; ++i) {
                #pragma unroll
                for (int reg = 0; reg < 4; ++reg) {
                    const int m = m0 + wy*64 + i*16 + quad*4 + reg;
                    const float ang = (float)(m & (SEQ-1)) * invf;
                    float sn, cs;
                    sincosf(ang, &sn, &cs);
                    const float x1 = acc[i][jj][reg];
                    const float x2 = acc[i][jj+2][reg];
                    acc[i][jj][reg]   = x1*cs - x2*sn;
                    acc[i][jj+2][reg] = x2*cs + x1*sn;
                }
            }
        }
    }

    #pragma unroll
    for (int j = 0; j < 4; ++j) {
        const int c = nloc + wx*64 + j*16 + frow;
        #pragma unroll
        for (int i = 0; i < 4; ++i) {
            #pragma unroll
            for (int reg = 0; reg < 4; ++reg) {
                const int m = m0 + wy*64 + i*16 + quad*4 + reg;
                const float val = acc[i][j][reg];
                if (mode == 1) {
                    ((float*)ga.dst[seg])[(size_t)m*1024 + c] = val;
                } else if (mode == 2) {
                    // V^T: [b][c][s], b = m>>10, s = m&1023
                    ((u16*)ga.dst[seg])[((size_t)(m >> 10) << 20) + (size_t)c*1024 + (m & 1023)] = f2bf(val);
                } else {
                    ((u16*)ga.dst[seg])[(size_t)m*1024 + c] = f2bf(val);
                }
            }
        }
    }
}

// ---------------------------------------------------------------------------
// MFMA flash attention. Block = 4 waves; one (b,h), 64 q-rows (16 per wave).
// K-tiles of 64 keys. K/V staged via global_load_lds w/ XOR chunk swizzle.
//   s_a = [qa | j2h*qb] . [ka|kb]^T ; s_b = [qa|qb] . [kb|ka]^T  (K=128)
//   mag = sqrt(s_a^2+s_b^2+1e-8)/8 ; causal ; online softmax ; O += P.V
// V supplied transposed: vt[b][c=h*64+d][s].
// ---------------------------------------------------------------------------
__global__ __launch_bounds__(256) void attn_mfma(
    const u16* __restrict__ qa, const u16* __restrict__ qb,
    const u16* __restrict__ ka, const u16* __restrict__ kb,
    const u16* __restrict__ vat, const u16* __restrict__ vbt,
    const float* __restrict__ thetas,
    u16* __restrict__ oa, u16* __restrict__ ob)
{
    __shared__ u16 sKa[64][64];
    __shared__ u16 sKb[64][64];
    __shared__ u16 sVa[64][64];
    __shared__ u16 sVb[64][64];
    __shared__ u16 sP[4][16][72];   // wave-private P, stride 72 hw (16B-aligned rows)

    const int t    = threadIdx.x;
    const int lane = t & 63;
    const int w    = t >> 6;
    const int L15  = lane & 15;
    const int quad = lane >> 4;

    // work-balanced mapping: bid<256 -> qt=15..8 ; bid>=256 -> qt=0..7
    const int bid  = blockIdx.x;
    const int aa   = (bid >> 5) & 7;
    const int qt   = (bid >> 8) ? aa : (15 - aa);
    const int bh   = bid & 31;
    const int h    = bh & 15;
    const int b    = bh >> 4;

    const float j2h = sinf(2.0f * thetas[h]) - 1.0f;

    // ---- Q fragments (A-operand: m=lane&15, k=quad*8+j), 2 slices of 32 ----
    const int   qrow  = qt*64 + w*16 + L15;
    const size_t qbase = (size_t)(b*SEQ + qrow) * EMB + h*DH;
    short8 fqa[2], fqb[2], fjqb[2];
    fqa[0] = *(const short8*)(qa + qbase + quad*8);
    fqa[1] = *(const short8*)(qa + qbase + 32 + quad*8);
    fqb[0] = *(const short8*)(qb + qbase + quad*8);
    fqb[1] = *(const short8*)(qb + qbase + 32 + quad*8);
    #pragma unroll
    for (int s2 = 0; s2 < 2; ++s2) {
        short8 src = fqb[s2], dst;
        #pragma unroll
        for (int j = 0; j < 8; ++j)
            dst[j] = (short)f2bf(bf2f((u16)src[j]) * j2h);
        fjqb[s2] = dst;
    }

    f32x4 acc_a[4] = {};
    f32x4 acc_b[4] = {};
    float m_run[4] = {-1e30f, -1e30f, -1e30f, -1e30f};
    float l_run[4] = {0.f, 0.f, 0.f, 0.f};

    const int subrow = lane >> 3;
    const int g      = (lane & 7) ^ subrow;
    const int swz    = L15 & 7;        // read-side swizzle key

    for (int kt = 0; kt <= qt; ++kt) {
        __syncthreads();
        #pragma unroll
        for (int i = 0; i < 2; ++i) {
            const int row = w*16 + i*8 + subrow;
            const int ldsoff = (w*16 + i*8) * 128;
            const size_t ktok = (size_t)(b*SEQ + kt*64 + row);
            async_copy16((const char*)ka + ktok*2048 + h*128 + g*16,
                         (char*)&sKa[0][0] + ldsoff);
            async_copy16((const char*)kb + ktok*2048 + h*128 + g*16,
                         (char*)&sKb[0][0] + ldsoff);
            const size_t vrow = (size_t)b*1048576 + (size_t)(h*64 + row)*1024 + kt*64;
            async_copy16((const char*)vat + vrow*2 + g*16,
                         (char*)&sVa[0][0] + ldsoff);
            async_copy16((const char*)vbt + vrow*2 + g*16,
                         (char*)&sVb[0][0] + ldsoff);
        }
        __syncthreads();

        // ---- scores ----
        f32x4 sa[4] = {}, sb[4] = {};
        #pragma unroll
        for (int n = 0; n < 4; ++n) {
            const u16* rKa = &sKa[n*16 + L15][0];
            const u16* rKb = &sKb[n*16 + L15][0];
            short8 ka0 = *(const short8*)(rKa + (( quad      ^ swz) << 3));
            short8 ka1 = *(const short8*)(rKa + (((4 + quad) ^ swz) << 3));
            short8 kb0 = *(const short8*)(rKb + (( quad      ^ swz) << 3));
            short8 kb1 = *(const short8*)(rKb + (((4 + quad) ^ swz) << 3));
            sa[n] = __builtin_amdgcn_mfma_f32_16x16x32_bf16(fqa[0],  ka0, sa[n], 0, 0, 0);
            sa[n] = __builtin_amdgcn_mfma_f32_16x16x32_bf16(fqa[1],  ka1, sa[n], 0, 0, 0);
            sa[n] = __builtin_amdgcn_mfma_f32_16x16x32_bf16(fjqb[0], kb0, sa[n], 0, 0, 0);
            sa[n] = __builtin_amdgcn_mfma_f32_16x16x32_bf16(fjqb[1], kb1, sa[n], 0, 0, 0);
            sb[n] = __builtin_amdgcn_mfma_f32_16x16x32_bf16(fqa[0],  kb0, sb[n], 0, 0, 0);
            sb[n] = __builtin_amdgcn_mfma_f32_16x16x32_bf16(fqa[1],  kb1, sb[n], 0, 0, 0);
            sb[n] = __builtin_amdgcn_mfma_f32_16x16x32_bf16(fqb[0],  ka0, sb[n], 0, 0, 0);
            sb[n] = __builtin_amdgcn_mfma_f32_16x16x32_bf16(fqb[1],  ka1, sb[n], 0, 0, 0);
        }

        // ---- magnitude + causal mask ----
        float mag[4][4];
        #pragma unroll
        for (int n = 0; n < 4; ++n)
            #pragma unroll
            for (int r = 0; r < 4; ++r) {
                const float A = sa[n][r], B = sb[n][r];
                mag[n][r] = sqrtf(A*A + B*B + 1e-8f) * 0.125f;
            }
        if (kt == qt) {
            #pragma unroll
            for (int n = 0; n < 4; ++n)
                #pragma unroll
                for (int r = 0; r < 4; ++r)
                    if (n*16 + L15 > w*16 + quad*4 + r) mag[n][r] = -1e9f;
        }

        // ---- online softmax ----
        float rmax[4], psum[4], alpha[4];
        #pragma unroll
        for (int r = 0; r < 4; ++r) {
            float mx = fmaxf(fmaxf(mag[0][r], mag[1][r]), fmaxf(mag[2][r], mag[3][r]));
            #pragma unroll
            for (int off = 8; off >= 1; off >>= 1)
                mx = fmaxf(mx, __shfl_xor(mx, off, 64));
            rmax[r] = mx;
        }
        float p[4][4];
        #pragma unroll
        for (int r = 0; r < 4; ++r) {
            const float m_new = fmaxf(m_run[r], rmax[r]);
            alpha[r] = expf(m_run[r] - m_new);
            m_run[r] = m_new;
            float ps = 0.f;
            #pragma unroll
            for (int n = 0; n < 4; ++n) {
                p[n][r] = expf(mag[n][r] - m_new);
                ps += p[n][r];
            }
            #pragma unroll
            for (int off = 8; off >= 1; off >>= 1)
                ps += __shfl_xor(ps, off, 64);
            psum[r] = ps;
            l_run[r] = l_run[r] * alpha[r] + psum[r];
        }
        #pragma unroll
        for (int n = 0; n < 4; ++n)
            #pragma unroll
            for (int r = 0; r < 4; ++r) {
                acc_a[n][r] *= alpha[r];
                acc_b[n][r] *= alpha[r];
            }

        // ---- P -> LDS (wave-private), re-enter as A-operand ----
        #pragma unroll
        for (int n = 0; n < 4; ++n)
            #pragma unroll
            for (int r = 0; r < 4; ++r)
                sP[w][quad*4 + r][n*16 + L15] = f2bf(p[n][r]);

        short8 pf0 = *(const short8*)&sP[w][L15][quad*8];
        short8 pf1 = *(const short8*)&sP[w][L15][32 + quad*8];

        // ---- PV ----
        #pragma unroll
        for (int n = 0; n < 4; ++n) {
            const u16* rVa = &sVa[n*16 + L15][0];
            const u16* rVb = &sVb[n*16 + L15][0];
            short8 va0 = *(const short8*)(rVa + (( quad      ^ swz) << 3));
            short8 va1 = *(const short8*)(rVa + (((4 + quad) ^ swz) << 3));
            short8 vb0 = *(const short8*)(rVb + (( quad      ^ swz) << 3));
            short8 vb1 = *(const short8*)(rVb + (((4 + quad) ^ swz) << 3));
            acc_a[n] = __builtin_amdgcn_mfma_f32_16x16x32_bf16(pf0, va0, acc_a[n], 0, 0, 0);
            acc_a[n] = __builtin_amdgcn_mfma_f32_16x16x32_bf16(pf1, va1, acc_a[n], 0, 0, 0);
            acc_b[n] = __builtin_amdgcn_mfma_f32_16x16x32_bf16(pf0, vb0, acc_b[n], 0, 0, 0);
            acc_b[n] = __builtin_amdgcn_mfma_f32_16x16x32_bf16(pf1, vb1, acc_b[n], 0, 0, 0);
        }
    }

    // ---- write out (C layout: row=quad*4+reg, col=n*16+L15) ----
    float inv[4];
    #pragma unroll
    for (int r = 0; r < 4; ++r) inv[r] = 1.0f / l_run[r];
    #pragma unroll
    for (int reg = 0; reg < 4; ++reg) {
        const size_t tok = (size_t)(b*SEQ + qt*64 + w*16 + quad*4 + reg);
        #pragma unroll
        for (int n = 0; n < 4; ++n) {
            const size_t idx = tok*EMB + h*DH + n*16 + L15;
            oa[idx] = f2bf(acc_a[n][reg] * inv[reg]);
            ob[idx] = f2bf(acc_b[n][reg] * inv[reg]);
        }
    }
}

// ---------------------------------------------------------------------------
extern "C" void kernel_launch(void* const* d_in, const int* in_sizes, int n_in,
                              void* d_out, int out_size, void* d_ws, size_t ws_size,
                              hipStream_t stream)
{
    const float* x_q_a  = (const float*)d_in[0];
    const float* x_q_b  = (const float*)d_in[1];
    const float* x_kv_a = (const float*)d_in[2];
    const float* x_kv_b = (const float*)d_in[3];
    const float* theta    = (const float*)d_in[5];
    const float* thetas_h = (const float*)d_in[6];
    const float* q_wa = (const float*)d_in[7];
    const float* q_wb = (const float*)d_in[8];
    const float* q_ba = (const float*)d_in[9];
    const float* q_bb = (const float*)d_in[10];
    const float* k_wa = (const float*)d_in[11];
    const float* k_wb = (const float*)d_in[12];
    const float* k_ba = (const float*)d_in[13];
    const float* k_bb = (const float*)d_in[14];
    const float* v_wa = (const float*)d_in[15];
    const float* v_wb = (const float*)d_in[16];
    const float* v_ba = (const float*)d_in[17];
    const float* v_bb = (const float*)d_in[18];
    const float* o_wa = (const float*)d_in[19];
    const float* o_wb = (const float*)d_in[20];
    const float* o_ba = (const float*)d_in[21];
    const float* o_bb = (const float*)d_in[22];

    u16* W = (u16*)d_ws;
    const size_t XN = (size_t)BSE;
    const size_t WN = (size_t)EMB*EMB;
    u16* xq_a16  = W;
    u16* xq_b16  = W + XN;
    u16* xkv_a16 = W + 2*XN;
    u16* xkv_b16 = W + 3*XN;
    u16* wbase   = W + 4*XN;
    u16* q_wa16  = wbase;
    u16* q_wb16  = wbase + WN;
    u16* k_wa16  = wbase + 2*WN;
    u16* k_wb16  = wbase + 3*WN;
    u16* v_wa16  = wbase + 4*WN;
    u16* v_wb16  = wbase + 5*WN;
    u16* o_wa16  = wbase + 6*WN;
    u16* o_wb16  = wbase + 7*WN;
    u16* q_wbs16 = wbase + 8*WN;
    u16* k_wbs16 = wbase + 9*WN;
    u16* v_wbs16 = wbase + 10*WN;
    u16* o_wbs16 = wbase + 11*WN;
    u16* qkv     = wbase + 12*WN;
    u16* qa16 = qkv;
    u16* qb16 = qkv + XN;
    u16* ka16 = qkv + 2*XN;
    u16* kb16 = qkv + 3*XN;
    u16* vat16 = qkv + 4*XN;   // transposed [b][c][s]
    u16* vbt16 = qkv + 5*XN;
    u16* ao16 = xq_a16;        // alias: xq region free after QKV GEMM
    u16* bo16 = xq_b16;

    float* out_a = (float*)d_out;
    float* out_b = out_a + (size_t)BSE;

    // ---- 1. pack to bf16 ----
    PackArgs pa;
    const float* psrc[16] = { x_q_a, x_q_b, x_kv_a, x_kv_b,
                              q_wa, q_wb, k_wa, k_wb, v_wa, v_wb, o_wa, o_wb,
                              q_wb, k_wb, v_wb, o_wb };
    u16* pdst[16] = { xq_a16, xq_b16, xkv_a16, xkv_b16,
                      q_wa16, q_wb16, k_wa16, k_wb16, v_wa16, v_wb16, o_wa16, o_wb16,
                      q_wbs16, k_wbs16, v_wbs16, o_wbs16 };
    for (int e = 0; e < 16; ++e) {
        pa.src[e] = psrc[e];
        pa.dst[e] = pdst[e];
        pa.n[e]   = (e < 4) ? (int)XN : (int)WN;
        pa.scaled[e] = (e >= 12) ? 1 : 0;
    }
    pack_kernel<<<dim3(XN/(256*4), 16), 256, 0, stream>>>(pa, theta);

    // ---- 2. QKV projections: ONE dispatch, 6 segments, RoPE fused (mode 3) ----
    GemmArgs g12;
    // seg 0: qa   seg 1: qb   seg 2: ka   seg 3: kb   seg 4: va^T  seg 5: vb^T
    const u16* a1s[6] = { xq_a16, xq_a16, xkv_a16, xkv_a16, xkv_a16, xkv_a16 };
    const u16* a2s[6] = { xq_b16, xq_b16, xkv_b16, xkv_b16, xkv_b16, xkv_b16 };
    const u16* blo[6] = { q_wa16, q_wb16, k_wa16, k_wb16, v_wa16, v_wb16 };
    const u16* bhi[6] = { q_wbs16, q_wa16, k_wbs16, k_wa16, v_wbs16, v_wa16 };
    const float* bia[6] = { q_ba, q_bb, k_ba, k_bb, v_ba, v_bb };
    void* dsts[6] = { qa16, qb16, ka16, kb16, vat16, vbt16 };
    const int modes[6] = { 3, 3, 3, 3, 2, 2 };
    for (int s = 0; s < 6; ++s) {
        g12.A1s[s] = a1s[s]; g12.A2s[s] = a2s[s];
        g12.Blo[s] = blo[s]; g12.Bhi[s] = bhi[s];
        g12.bias[s] = bia[s]; g12.dst[s] = dsts[s]; g12.mode[s] = modes[s];
    }
    for (int s = 6; s < 8; ++s) {  // unused slots
        g12.A1s[s] = a1s[0]; g12.A2s[s] = a2s[0];
        g12.Blo[s] = blo[0]; g12.Bhi[s] = bhi[0];
        g12.bias[s] = bia[0]; g12.dst[s] = dsts[0]; g12.mode[s] = 0;
    }
    mfma_gemm<<<dim3(48, MROWS/128), 256, 0, stream>>>(g12);

    // ---- 3. attention (MFMA flash) ----
    attn_mfma<<<BATCH*NH*(SEQ/64), 256, 0, stream>>>(qa16, qb16, ka16, kb16,
                                                     vat16, vbt16, thetas_h, ao16, bo16);

    // ---- 4. output projection (fp32 out) ----
    GemmArgs g3;
    for (int s = 0; s < 8; ++s) {
        g3.A1s[s] = ao16; g3.A2s[s] = bo16;
        g3.Blo[s] = o_wa16; g3.Bhi[s] = o_wbs16;
        g3.bias[s] = o_ba; g3.dst[s] = out_a; g3.mode[s] = 1;
    }
    g3.Blo[1] = o_wb16; g3.Bhi[1] = o_wa16; g3.bias[1] = o_bb; g3.dst[1] = out_b;
    mfma_gemm<<<dim3(16, MROWS/128), 256, 0, stream>>>(g3);
}

// Round 6
// 341.642 us; speedup vs baseline: 4.7772x; 1.0088x over previous
//
#include <hip/hip_runtime.h>
#include <math.h>
#include <stdint.h>

#define BATCH 2
#define SEQ   1024
#define EMB   1024
#define NH    16
#define DH    64
#define BSE   (BATCH*SEQ*EMB)   /* 2097152 elements per (B,S,E) tensor */
#define MROWS (BATCH*SEQ)       /* 2048 */

typedef unsigned short u16;
typedef __attribute__((ext_vector_type(8))) short short8;
typedef __attribute__((ext_vector_type(4))) float f32x4;

__device__ __forceinline__ float bf2f(u16 u) {
    return __uint_as_float(((unsigned int)u) << 16);
}
__device__ __forceinline__ u16 f2bf(float f) {
    unsigned int x = __float_as_uint(f);
    x += 0x7FFFu + ((x >> 16) & 1u);   // round-to-nearest-even
    return (u16)(x >> 16);
}

__device__ __forceinline__ void async_copy16(const void* g, void* l) {
    __builtin_amdgcn_global_load_lds(
        (const __attribute__((address_space(1))) unsigned int*)g,
        (__attribute__((address_space(3))) unsigned int*)l,
        16, 0, 0);
}

// ---------------------------------------------------------------------------
// Pack: fp32 -> bf16 elementwise, 16 tensors in one launch (blockIdx.y=entry).
// scaled entries multiply by j2 = sin(2*theta)-1 first.
// ---------------------------------------------------------------------------
struct PackArgs {
    const float* src[16];
    u16*         dst[16];
    int          n[16];
    int          scaled[16];
};

__global__ __launch_bounds__(256) void pack_kernel(PackArgs pa, const float* __restrict__ theta)
{
    const int e = blockIdx.y;
    const int i = (blockIdx.x * 256 + threadIdx.x) * 4;
    if (i >= pa.n[e]) return;
    float sc = 1.0f;
    if (pa.scaled[e]) sc = sinf(2.0f * theta[0]) - 1.0f;
    float4 v = *(const float4*)(pa.src[e] + i);
    u16* d = pa.dst[e] + i;
    ushort4 o;
    o.x = f2bf(v.x * sc); o.y = f2bf(v.y * sc);
    o.z = f2bf(v.z * sc); o.w = f2bf(v.w * sc);
    *(ushort4*)d = o;
}

// ---------------------------------------------------------------------------
// MFMA bf16 GEMM with virtual K-concat (K=2048), up to 8 N-segments of 1024.
//   C[m][c] = sum_k A1[m][k]*Blo[c][k] + A2[m][k]*Bhi[c][k] + bias[c]
// mode: 0 = bf16 [m][c] store, 1 = fp32 [m][c] store,
//       2 = bf16 transposed store dst[b][c][s]  (V^T),
//       3 = bf16 [m][c] store with fused RoPE (q/k heads, Dh=64, native sin/cos)
// 128x128 tile, BK=32, 4 waves, 16x16x32 MFMA, global_load_lds width-16.
// Grid: x = m-tile (fastest) for L2 segment locality, y = n-tile.
// ---------------------------------------------------------------------------
struct GemmArgs {
    const u16*   A1s[8];
    const u16*   A2s[8];
    const u16*   Blo[8];
    const u16*   Bhi[8];
    const float* bias[8];
    void*        dst[8];
    int          mode[8];
};

__global__ __launch_bounds__(256) void mfma_gemm(GemmArgs ga)
{
    __shared__ u16 sA[128][32];
    __shared__ u16 sB[128][32];

    const int t    = threadIdx.x;
    const int lane = t & 63;
    const int w    = t >> 6;
    const int wx   = w & 1;
    const int wy   = w >> 1;
    const int n0   = blockIdx.y * 128;   // n-tile = slow index (L2 locality)
    const int m0   = blockIdx.x * 128;   // m-tile = fast index
    const int seg  = n0 >> 10;
    const int nloc = n0 & 1023;

    const int srow = t >> 2;          // staging row within 64-row round
    const int sb   = (t & 3) * 16;    // staging byte offset within 64-B row

    f32x4 acc[4][4] = {};

    const char* A1 = (const char*)ga.A1s[seg];
    const char* A2 = (const char*)ga.A2s[seg];
    const char* Bl = (const char*)ga.Blo[seg];
    const char* Bh = (const char*)ga.Bhi[seg];

    const int frow = lane & 15;
    const int quad = lane >> 4;

    for (int kt = 0; kt < 64; ++kt) {
        const char* As = (kt & 32) ? A2 : A1;
        const char* Bs = (kt & 32) ? Bh : Bl;
        const size_t kbyte = (size_t)(kt & 31) * 64;

        __syncthreads();
        #pragma unroll
        for (int r = 0; r < 2; ++r) {
            const int row = r*64 + srow;
            const int ldsoff = (r*64 + w*16) * 64;
            async_copy16(As + (size_t)(m0 + row)*2048 + kbyte + sb,
                         (char*)&sA[0][0] + ldsoff);
            async_copy16(Bs + (size_t)(nloc + row)*2048 + kbyte + sb,
                         (char*)&sB[0][0] + ldsoff);
        }
        __syncthreads();

        short8 af[4], bfr[4];
        #pragma unroll
        for (int i = 0; i < 4; ++i)
            af[i] = *(const short8*)&sA[wy*64 + i*16 + frow][quad*8];
        #pragma unroll
        for (int j = 0; j < 4; ++j)
            bfr[j] = *(const short8*)&sB[wx*64 + j*16 + frow][quad*8];

        #pragma unroll
        for (int i = 0; i < 4; ++i)
            #pragma unroll
            for (int j = 0; j < 4; ++j)
                acc[i][j] = __builtin_amdgcn_mfma_f32_16x16x32_bf16(
                                af[i], bfr[j], acc[i][j], 0, 0, 0);
    }

    // ---- epilogue: C/D layout col=lane&15, row=quad*4+reg ----
    const float* bias = ga.bias[seg];
    const int mode = ga.mode[seg];

    // bias (in place)
    #pragma unroll
    for (int j = 0; j < 4; ++j) {
        const int c = nloc + wx*64 + j*16 + frow;
        const float bv = bias[c];
        #pragma unroll
        for (int i = 0; i < 4; ++i)
            #pragma unroll
            for (int reg = 0; reg < 4; ++reg)
                acc[i][j][reg] += bv;
    }

    // fused RoPE via native v_sin/v_cos (revolutions, fract-reduced).
    // cols within head pair as (j, j+2) in the same thread; d = jj*16+frow.
    if (mode == 3) {
        #pragma unroll
        for (int jj = 0; jj < 2; ++jj) {
            // 10000^{-d/32} / (2*pi)
            const float invf_rev = expf(-(float)(jj*16 + frow) * 0.28782313662425576f)
                                   * 0.15915494309189535f;
            #pragma unroll
            for (int i = 0; i < 4; ++i) {
                #pragma unroll
                for (int reg = 0; reg < 4; ++reg) {
                    const int m = m0 + wy*64 + i*16 + quad*4 + reg;
                    float rev = (float)(m & (SEQ-1)) * invf_rev;
                    rev -= floorf(rev);
                    const float sn = __builtin_amdgcn_sinf(rev);  // sin(2*pi*rev)
                    const float cs = __builtin_amdgcn_cosf(rev);
                    const float x1 = acc[i][jj][reg];
                    const float x2 = acc[i][jj+2][reg];
                    acc[i][jj][reg]   = x1*cs - x2*sn;
                    acc[i][jj+2][reg] = x2*cs + x1*sn;
                }
            }
        }
    }

    #pragma unroll
    for (int j = 0; j < 4; ++j) {
        const int c = nloc + wx*64 + j*16 + frow;
        #pragma unroll
        for (int i = 0; i < 4; ++i) {
            #pragma unroll
            for (int reg = 0; reg < 4; ++reg) {
                const int m = m0 + wy*64 + i*16 + quad*4 + reg;
                const float val = acc[i][j][reg];
                if (mode == 1) {
                    ((float*)ga.dst[seg])[(size_t)m*1024 + c] = val;
                } else if (mode == 2) {
                    // V^T: [b][c][s], b = m>>10, s = m&1023
                    ((u16*)ga.dst[seg])[((size_t)(m >> 10) << 20) + (size_t)c*1024 + (m & 1023)] = f2bf(val);
                } else {
                    ((u16*)ga.dst[seg])[(size_t)m*1024 + c] = f2bf(val);
                }
            }
        }
    }
}

// ---------------------------------------------------------------------------
// MFMA flash attention. Block = 4 waves; one (b,h), 64 q-rows (16 per wave).
// K-tiles of 64 keys. K/V staged via global_load_lds w/ XOR chunk swizzle.
//   s_a = [qa | j2h*qb] . [ka|kb]^T ; s_b = [qa|qb] . [kb|ka]^T  (K=128)
//   mag = sqrt(s_a^2+s_b^2+1e-8)/8 ; causal ; online softmax ; O += P.V
// V supplied transposed: vt[b][c=h*64+d][s].
// ---------------------------------------------------------------------------
__global__ __launch_bounds__(256) void attn_mfma(
    const u16* __restrict__ qa, const u16* __restrict__ qb,
    const u16* __restrict__ ka, const u16* __restrict__ kb,
    const u16* __restrict__ vat, const u16* __restrict__ vbt,
    const float* __restrict__ thetas,
    u16* __restrict__ oa, u16* __restrict__ ob)
{
    __shared__ u16 sKa[64][64];
    __shared__ u16 sKb[64][64];
    __shared__ u16 sVa[64][64];
    __shared__ u16 sVb[64][64];
    __shared__ u16 sP[4][16][72];   // wave-private P, stride 72 hw (16B-aligned rows)

    const int t    = threadIdx.x;
    const int lane = t & 63;
    const int w    = t >> 6;
    const int L15  = lane & 15;
    const int quad = lane >> 4;

    // work-balanced mapping: bid<256 -> qt=15..8 ; bid>=256 -> qt=0..7
    const int bid  = blockIdx.x;
    const int aa   = (bid >> 5) & 7;
    const int qt   = (bid >> 8) ? aa : (15 - aa);
    const int bh   = bid & 31;
    const int h    = bh & 15;
    const int b    = bh >> 4;

    const float j2h = sinf(2.0f * thetas[h]) - 1.0f;

    // ---- Q fragments (A-operand: m=lane&15, k=quad*8+j), 2 slices of 32 ----
    const int   qrow  = qt*64 + w*16 + L15;
    const size_t qbase = (size_t)(b*SEQ + qrow) * EMB + h*DH;
    short8 fqa[2], fqb[2], fjqb[2];
    fqa[0] = *(const short8*)(qa + qbase + quad*8);
    fqa[1] = *(const short8*)(qa + qbase + 32 + quad*8);
    fqb[0] = *(const short8*)(qb + qbase + quad*8);
    fqb[1] = *(const short8*)(qb + qbase + 32 + quad*8);
    #pragma unroll
    for (int s2 = 0; s2 < 2; ++s2) {
        short8 src = fqb[s2], dst;
        #pragma unroll
        for (int j = 0; j < 8; ++j)
            dst[j] = (short)f2bf(bf2f((u16)src[j]) * j2h);
        fjqb[s2] = dst;
    }

    f32x4 acc_a[4] = {};
    f32x4 acc_b[4] = {};
    float m_run[4] = {-1e30f, -1e30f, -1e30f, -1e30f};
    float l_run[4] = {0.f, 0.f, 0.f, 0.f};

    const int subrow = lane >> 3;
    const int g      = (lane & 7) ^ subrow;
    const int swz    = L15 & 7;        // read-side swizzle key

    for (int kt = 0; kt <= qt; ++kt) {
        __syncthreads();
        #pragma unroll
        for (int i = 0; i < 2; ++i) {
            const int row = w*16 + i*8 + subrow;
            const int ldsoff = (w*16 + i*8) * 128;
            const size_t ktok = (size_t)(b*SEQ + kt*64 + row);
            async_copy16((const char*)ka + ktok*2048 + h*128 + g*16,
                         (char*)&sKa[0][0] + ldsoff);
            async_copy16((const char*)kb + ktok*2048 + h*128 + g*16,
                         (char*)&sKb[0][0] + ldsoff);
            const size_t vrow = (size_t)b*1048576 + (size_t)(h*64 + row)*1024 + kt*64;
            async_copy16((const char*)vat + vrow*2 + g*16,
                         (char*)&sVa[0][0] + ldsoff);
            async_copy16((const char*)vbt + vrow*2 + g*16,
                         (char*)&sVb[0][0] + ldsoff);
        }
        __syncthreads();

        // ---- scores ----
        f32x4 sa[4] = {}, sb[4] = {};
        #pragma unroll
        for (int n = 0; n < 4; ++n) {
            const u16* rKa = &sKa[n*16 + L15][0];
            const u16* rKb = &sKb[n*16 + L15][0];
            short8 ka0 = *(const short8*)(rKa + (( quad      ^ swz) << 3));
            short8 ka1 = *(const short8*)(rKa + (((4 + quad) ^ swz) << 3));
            short8 kb0 = *(const short8*)(rKb + (( quad      ^ swz) << 3));
            short8 kb1 = *(const short8*)(rKb + (((4 + quad) ^ swz) << 3));
            sa[n] = __builtin_amdgcn_mfma_f32_16x16x32_bf16(fqa[0],  ka0, sa[n], 0, 0, 0);
            sa[n] = __builtin_amdgcn_mfma_f32_16x16x32_bf16(fqa[1],  ka1, sa[n], 0, 0, 0);
            sa[n] = __builtin_amdgcn_mfma_f32_16x16x32_bf16(fjqb[0], kb0, sa[n], 0, 0, 0);
            sa[n] = __builtin_amdgcn_mfma_f32_16x16x32_bf16(fjqb[1], kb1, sa[n], 0, 0, 0);
            sb[n] = __builtin_amdgcn_mfma_f32_16x16x32_bf16(fqa[0],  kb0, sb[n], 0, 0, 0);
            sb[n] = __builtin_amdgcn_mfma_f32_16x16x32_bf16(fqa[1],  kb1, sb[n], 0, 0, 0);
            sb[n] = __builtin_amdgcn_mfma_f32_16x16x32_bf16(fqb[0],  ka0, sb[n], 0, 0, 0);
            sb[n] = __builtin_amdgcn_mfma_f32_16x16x32_bf16(fqb[1],  ka1, sb[n], 0, 0, 0);
        }

        // ---- magnitude + causal mask ----
        float mag[4][4];
        #pragma unroll
        for (int n = 0; n < 4; ++n)
            #pragma unroll
            for (int r = 0; r < 4; ++r) {
                const float A = sa[n][r], B = sb[n][r];
                mag[n][r] = sqrtf(A*A + B*B + 1e-8f) * 0.125f;
            }
        if (kt == qt) {
            #pragma unroll
            for (int n = 0; n < 4; ++n)
                #pragma unroll
                for (int r = 0; r < 4; ++r)
                    if (n*16 + L15 > w*16 + quad*4 + r) mag[n][r] = -1e9f;
        }

        // ---- online softmax ----
        float rmax[4], psum[4], alpha[4];
        #pragma unroll
        for (int r = 0; r < 4; ++r) {
            float mx = fmaxf(fmaxf(mag[0][r], mag[1][r]), fmaxf(mag[2][r], mag[3][r]));
            #pragma unroll
            for (int off = 8; off >= 1; off >>= 1)
                mx = fmaxf(mx, __shfl_xor(mx, off, 64));
            rmax[r] = mx;
        }
        float p[4][4];
        #pragma unroll
        for (int r = 0; r < 4; ++r) {
            const float m_new = fmaxf(m_run[r], rmax[r]);
            alpha[r] = expf(m_run[r] - m_new);
            m_run[r] = m_new;
            float ps = 0.f;
            #pragma unroll
            for (int n = 0; n < 4; ++n) {
                p[n][r] = expf(mag[n][r] - m_new);
                ps += p[n][r];
            }
            #pragma unroll
            for (int off = 8; off >= 1; off >>= 1)
                ps += __shfl_xor(ps, off, 64);
            psum[r] = ps;
            l_run[r] = l_run[r] * alpha[r] + psum[r];
        }
        #pragma unroll
        for (int n = 0; n < 4; ++n)
            #pragma unroll
            for (int r = 0; r < 4; ++r) {
                acc_a[n][r] *= alpha[r];
                acc_b[n][r] *= alpha[r];
            }

        // ---- P -> LDS (wave-private), re-enter as A-operand ----
        #pragma unroll
        for (int n = 0; n < 4; ++n)
            #pragma unroll
            for (int r = 0; r < 4; ++r)
                sP[w][quad*4 + r][n*16 + L15] = f2bf(p[n][r]);

        short8 pf0 = *(const short8*)&sP[w][L15][quad*8];
        short8 pf1 = *(const short8*)&sP[w][L15][32 + quad*8];

        // ---- PV ----
        #pragma unroll
        for (int n = 0; n < 4; ++n) {
            const u16* rVa = &sVa[n*16 + L15][0];
            const u16* rVb = &sVb[n*16 + L15][0];
            short8 va0 = *(const short8*)(rVa + (( quad      ^ swz) << 3));
            short8 va1 = *(const short8*)(rVa + (((4 + quad) ^ swz) << 3));
            short8 vb0 = *(const short8*)(rVb + (( quad      ^ swz) << 3));
            short8 vb1 = *(const short8*)(rVb + (((4 + quad) ^ swz) << 3));
            acc_a[n] = __builtin_amdgcn_mfma_f32_16x16x32_bf16(pf0, va0, acc_a[n], 0, 0, 0);
            acc_a[n] = __builtin_amdgcn_mfma_f32_16x16x32_bf16(pf1, va1, acc_a[n], 0, 0, 0);
            acc_b[n] = __builtin_amdgcn_mfma_f32_16x16x32_bf16(pf0, vb0, acc_b[n], 0, 0, 0);
            acc_b[n] = __builtin_amdgcn_mfma_f32_16x16x32_bf16(pf1, vb1, acc_b[n], 0, 0, 0);
        }
    }

    // ---- write out (C layout: row=quad*4+reg, col=n*16+L15) ----
    float inv[4];
    #pragma unroll
    for (int r = 0; r < 4; ++r) inv[r] = 1.0f / l_run[r];
    #pragma unroll
    for (int reg = 0; reg < 4; ++reg) {
        const size_t tok = (size_t)(b*SEQ + qt*64 + w*16 + quad*4 + reg);
        #pragma unroll
        for (int n = 0; n < 4; ++n) {
            const size_t idx = tok*EMB + h*DH + n*16 + L15;
            oa[idx] = f2bf(acc_a[n][reg] * inv[reg]);
            ob[idx] = f2bf(acc_b[n][reg] * inv[reg]);
        }
    }
}

// ---------------------------------------------------------------------------
extern "C" void kernel_launch(void* const* d_in, const int* in_sizes, int n_in,
                              void* d_out, int out_size, void* d_ws, size_t ws_size,
                              hipStream_t stream)
{
    const float* x_q_a  = (const float*)d_in[0];
    const float* x_q_b  = (const float*)d_in[1];
    const float* x_kv_a = (const float*)d_in[2];
    const float* x_kv_b = (const float*)d_in[3];
    const float* theta    = (const float*)d_in[5];
    const float* thetas_h = (const float*)d_in[6];
    const float* q_wa = (const float*)d_in[7];
    const float* q_wb = (const float*)d_in[8];
    const float* q_ba = (const float*)d_in[9];
    const float* q_bb = (const float*)d_in[10];
    const float* k_wa = (const float*)d_in[11];
    const float* k_wb = (const float*)d_in[12];
    const float* k_ba = (const float*)d_in[13];
    const float* k_bb = (const float*)d_in[14];
    const float* v_wa = (const float*)d_in[15];
    const float* v_wb = (const float*)d_in[16];
    const float* v_ba = (const float*)d_in[17];
    const float* v_bb = (const float*)d_in[18];
    const float* o_wa = (const float*)d_in[19];
    const float* o_wb = (const float*)d_in[20];
    const float* o_ba = (const float*)d_in[21];
    const float* o_bb = (const float*)d_in[22];

    u16* W = (u16*)d_ws;
    const size_t XN = (size_t)BSE;
    const size_t WN = (size_t)EMB*EMB;
    u16* xq_a16  = W;
    u16* xq_b16  = W + XN;
    u16* xkv_a16 = W + 2*XN;
    u16* xkv_b16 = W + 3*XN;
    u16* wbase   = W + 4*XN;
    u16* q_wa16  = wbase;
    u16* q_wb16  = wbase + WN;
    u16* k_wa16  = wbase + 2*WN;
    u16* k_wb16  = wbase + 3*WN;
    u16* v_wa16  = wbase + 4*WN;
    u16* v_wb16  = wbase + 5*WN;
    u16* o_wa16  = wbase + 6*WN;
    u16* o_wb16  = wbase + 7*WN;
    u16* q_wbs16 = wbase + 8*WN;
    u16* k_wbs16 = wbase + 9*WN;
    u16* v_wbs16 = wbase + 10*WN;
    u16* o_wbs16 = wbase + 11*WN;
    u16* qkv     = wbase + 12*WN;
    u16* qa16 = qkv;
    u16* qb16 = qkv + XN;
    u16* ka16 = qkv + 2*XN;
    u16* kb16 = qkv + 3*XN;
    u16* vat16 = qkv + 4*XN;   // transposed [b][c][s]
    u16* vbt16 = qkv + 5*XN;
    u16* ao16 = xq_a16;        // alias: xq region free after QKV GEMM
    u16* bo16 = xq_b16;

    float* out_a = (float*)d_out;
    float* out_b = out_a + (size_t)BSE;

    // ---- 1. pack to bf16 ----
    PackArgs pa;
    const float* psrc[16] = { x_q_a, x_q_b, x_kv_a, x_kv_b,
                              q_wa, q_wb, k_wa, k_wb, v_wa, v_wb, o_wa, o_wb,
                              q_wb, k_wb, v_wb, o_wb };
    u16* pdst[16] = { xq_a16, xq_b16, xkv_a16, xkv_b16,
                      q_wa16, q_wb16, k_wa16, k_wb16, v_wa16, v_wb16, o_wa16, o_wb16,
                      q_wbs16, k_wbs16, v_wbs16, o_wbs16 };
    for (int e = 0; e < 16; ++e) {
        pa.src[e] = psrc[e];
        pa.dst[e] = pdst[e];
        pa.n[e]   = (e < 4) ? (int)XN : (int)WN;
        pa.scaled[e] = (e >= 12) ? 1 : 0;
    }
    pack_kernel<<<dim3(XN/(256*4), 16), 256, 0, stream>>>(pa, theta);

    // ---- 2. QKV projections: ONE dispatch, 6 segments, RoPE fused (mode 3) ----
    GemmArgs g12;
    // seg 0: qa   seg 1: qb   seg 2: ka   seg 3: kb   seg 4: va^T  seg 5: vb^T
    const u16* a1s[6] = { xq_a16, xq_a16, xkv_a16, xkv_a16, xkv_a16, xkv_a16 };
    const u16* a2s[6] = { xq_b16, xq_b16, xkv_b16, xkv_b16, xkv_b16, xkv_b16 };
    const u16* blo[6] = { q_wa16, q_wb16, k_wa16, k_wb16, v_wa16, v_wb16 };
    const u16* bhi[6] = { q_wbs16, q_wa16, k_wbs16, k_wa16, v_wbs16, v_wa16 };
    const float* bia[6] = { q_ba, q_bb, k_ba, k_bb, v_ba, v_bb };
    void* dsts[6] = { qa16, qb16, ka16, kb16, vat16, vbt16 };
    const int modes[6] = { 3, 3, 3, 3, 2, 2 };
    for (int s = 0; s < 6; ++s) {
        g12.A1s[s] = a1s[s]; g12.A2s[s] = a2s[s];
        g12.Blo[s] = blo[s]; g12.Bhi[s] = bhi[s];
        g12.bias[s] = bia[s]; g12.dst[s] = dsts[s]; g12.mode[s] = modes[s];
    }
    for (int s = 6; s < 8; ++s) {  // unused slots
        g12.A1s[s] = a1s[0]; g12.A2s[s] = a2s[0];
        g12.Blo[s] = blo[0]; g12.Bhi[s] = bhi[0];
        g12.bias[s] = bia[0]; g12.dst[s] = dsts[0]; g12.mode[s] = 0;
    }
    mfma_gemm<<<dim3(MROWS/128, 48), 256, 0, stream>>>(g12);

    // ---- 3. attention (MFMA flash) ----
    attn_mfma<<<BATCH*NH*(SEQ/64), 256, 0, stream>>>(qa16, qb16, ka16, kb16,
                                                     vat16, vbt16, thetas_h, ao16, bo16);

    // ---- 4. output projection (fp32 out) ----
    GemmArgs g3;
    for (int s = 0; s < 8; ++s) {
        g3.A1s[s] = ao16; g3.A2s[s] = bo16;
        g3.Blo[s] = o_wa16; g3.Bhi[s] = o_wbs16;
        g3.bias[s] = o_ba; g3.dst[s] = out_a; g3.mode[s] = 1;
    }
    g3.Blo[1] = o_wb16; g3.Bhi[1] = o_wa16; g3.bias[1] = o_bb; g3.dst[1] = out_b;
    mfma_gemm<<<dim3(MROWS/128, 16), 256, 0, stream>>>(g3);
}

// Round 7
// 331.694 us; speedup vs baseline: 4.9205x; 1.0300x over previous
//
#include <hip/hip_runtime.h>
#include <math.h>
#include <stdint.h>

#define BATCH 2
#define SEQ   1024
#define EMB   1024
#define NH    16
#define DH    64
#define BSE   (BATCH*SEQ*EMB)   /* 2097152 elements per (B,S,E) tensor */
#define MROWS (BATCH*SEQ)       /* 2048 */

typedef unsigned short u16;
typedef __attribute__((ext_vector_type(8))) short short8;
typedef __attribute__((ext_vector_type(4))) float f32x4;

__device__ __forceinline__ float bf2f(u16 u) {
    return __uint_as_float(((unsigned int)u) << 16);
}
__device__ __forceinline__ u16 f2bf(float f) {
    unsigned int x = __float_as_uint(f);
    x += 0x7FFFu + ((x >> 16) & 1u);   // round-to-nearest-even
    return (u16)(x >> 16);
}

__device__ __forceinline__ void async_copy16(const void* g, void* l) {
    __builtin_amdgcn_global_load_lds(
        (const __attribute__((address_space(1))) unsigned int*)g,
        (__attribute__((address_space(3))) unsigned int*)l,
        16, 0, 0);
}

// ---------------------------------------------------------------------------
// Pack: fp32 -> bf16 elementwise, 16 tensors in one launch (blockIdx.y=entry).
// scaled entries multiply by j2 = sin(2*theta)-1 first.
// ---------------------------------------------------------------------------
struct PackArgs {
    const float* src[16];
    u16*         dst[16];
    int          n[16];
    int          scaled[16];
};

__global__ __launch_bounds__(256) void pack_kernel(PackArgs pa, const float* __restrict__ theta)
{
    const int e = blockIdx.y;
    const int i = (blockIdx.x * 256 + threadIdx.x) * 4;
    if (i >= pa.n[e]) return;
    float sc = 1.0f;
    if (pa.scaled[e]) sc = sinf(2.0f * theta[0]) - 1.0f;
    float4 v = *(const float4*)(pa.src[e] + i);
    u16* d = pa.dst[e] + i;
    ushort4 o;
    o.x = f2bf(v.x * sc); o.y = f2bf(v.y * sc);
    o.z = f2bf(v.z * sc); o.w = f2bf(v.w * sc);
    *(ushort4*)d = o;
}

// ---------------------------------------------------------------------------
// MFMA bf16 GEMM with virtual K-concat (K=2048), up to 8 N-segments of 1024.
//   C[m][c] = sum_k A1[m][k]*Blo[c][k] + A2[m][k]*Bhi[c][k] + bias[c]
// mode: 0 = bf16 [m][c] store,
//       1 = fp32 atomicAdd [m][c] (split-K; bias added by ko==0 only),
//       2 = bf16 transposed store dst[b][c][s]  (V^T)
// SPLITK=1: one block does full K (A1 then A2 halves).
// SPLITK=2: blockIdx.z = ko selects the K-half; partial sums atomically added.
// 128x128 tile, BK=32, 4 waves, 16x16x32 MFMA, global_load_lds width-16.
// ---------------------------------------------------------------------------
struct GemmArgs {
    const u16*   A1s[8];
    const u16*   A2s[8];
    const u16*   Blo[8];
    const u16*   Bhi[8];
    const float* bias[8];
    void*        dst[8];
    int          mode[8];
};

template<int SPLITK>
__global__ __launch_bounds__(256) void mfma_gemm(GemmArgs ga)
{
    __shared__ u16 sA[128][32];
    __shared__ u16 sB[128][32];

    const int t    = threadIdx.x;
    const int lane = t & 63;
    const int w    = t >> 6;
    const int wx   = w & 1;
    const int wy   = w >> 1;
    const int n0   = blockIdx.y * 128;   // n-tile = slow index
    const int m0   = blockIdx.x * 128;   // m-tile = fast index
    const int ko   = (SPLITK == 2) ? blockIdx.z : 0;
    const int seg  = n0 >> 10;
    const int nloc = n0 & 1023;

    const int srow = t >> 2;          // staging row within 64-row round
    const int sb   = (t & 3) * 16;    // staging byte offset within 64-B row

    f32x4 acc[4][4] = {};

    const char* A1 = (const char*)ga.A1s[seg];
    const char* A2 = (const char*)ga.A2s[seg];
    const char* Bl = (const char*)ga.Blo[seg];
    const char* Bh = (const char*)ga.Bhi[seg];
    if (SPLITK == 2 && ko) { A1 = A2; Bl = Bh; }

    const int frow = lane & 15;
    const int quad = lane >> 4;

    const int NKT = (SPLITK == 2) ? 32 : 64;
    for (int kt = 0; kt < NKT; ++kt) {
        const char* As = (SPLITK == 1 && (kt & 32)) ? A2 : A1;
        const char* Bs = (SPLITK == 1 && (kt & 32)) ? Bh : Bl;
        const size_t kbyte = (size_t)(kt & 31) * 64;

        __syncthreads();
        #pragma unroll
        for (int r = 0; r < 2; ++r) {
            const int row = r*64 + srow;
            const int ldsoff = (r*64 + w*16) * 64;
            async_copy16(As + (size_t)(m0 + row)*2048 + kbyte + sb,
                         (char*)&sA[0][0] + ldsoff);
            async_copy16(Bs + (size_t)(nloc + row)*2048 + kbyte + sb,
                         (char*)&sB[0][0] + ldsoff);
        }
        __syncthreads();

        short8 af[4], bfr[4];
        #pragma unroll
        for (int i = 0; i < 4; ++i)
            af[i] = *(const short8*)&sA[wy*64 + i*16 + frow][quad*8];
        #pragma unroll
        for (int j = 0; j < 4; ++j)
            bfr[j] = *(const short8*)&sB[wx*64 + j*16 + frow][quad*8];

        #pragma unroll
        for (int i = 0; i < 4; ++i)
            #pragma unroll
            for (int j = 0; j < 4; ++j)
                acc[i][j] = __builtin_amdgcn_mfma_f32_16x16x32_bf16(
                                af[i], bfr[j], acc[i][j], 0, 0, 0);
    }

    // ---- epilogue: C/D layout col=lane&15, row=quad*4+reg ----
    const float* bias = ga.bias[seg];
    const int mode = ga.mode[seg];

    #pragma unroll
    for (int j = 0; j < 4; ++j) {
        const int c = nloc + wx*64 + j*16 + frow;
        const float bv = (SPLITK == 2 && ko) ? 0.0f : bias[c];
        #pragma unroll
        for (int i = 0; i < 4; ++i) {
            #pragma unroll
            for (int reg = 0; reg < 4; ++reg) {
                const int m = m0 + wy*64 + i*16 + quad*4 + reg;
                const float val = acc[i][j][reg] + bv;
                if (mode == 1) {
                    if (SPLITK == 2)
                        atomicAdd((float*)ga.dst[seg] + (size_t)m*1024 + c, val);
                    else
                        ((float*)ga.dst[seg])[(size_t)m*1024 + c] = val;
                } else if (mode == 2) {
                    // V^T: [b][c][s], b = m>>10, s = m&1023
                    ((u16*)ga.dst[seg])[((size_t)(m >> 10) << 20) + (size_t)c*1024 + (m & 1023)] = f2bf(val);
                } else {
                    ((u16*)ga.dst[seg])[(size_t)m*1024 + c] = f2bf(val);
                }
            }
        }
    }
}

// ---------------------------------------------------------------------------
// RoPE, in place on (B,S,E) bf16; pair (d, d+32) within each head.
// grid = (B*S*H*32/256, 4 tensors)
// ---------------------------------------------------------------------------
__global__ __launch_bounds__(256) void rope_kernel(
    u16* qa, u16* qb, u16* ka, u16* kb)
{
    u16* p;
    switch (blockIdx.y) {
        case 0:  p = qa; break;
        case 1:  p = qb; break;
        case 2:  p = ka; break;
        default: p = kb; break;
    }
    const int i   = blockIdx.x * 256 + threadIdx.x;
    const int d   = i & 31;
    const int hh  = (i >> 5) & (NH - 1);
    const int row = i >> 9;
    const int s   = row & (SEQ - 1);
    const size_t base = (size_t)row * EMB + hh * DH;

    float x1 = bf2f(p[base + d]);
    float x2 = bf2f(p[base + d + 32]);
    // 10000^{-d/32} / (2*pi); sin/cos in revolutions via native units
    const float invf_rev = expf(-(float)d * 0.28782313662425576f) * 0.15915494309189535f;
    float rev = (float)s * invf_rev;
    rev -= floorf(rev);
    const float sn = __builtin_amdgcn_sinf(rev);
    const float cs = __builtin_amdgcn_cosf(rev);
    p[base + d]      = f2bf(x1 * cs - x2 * sn);
    p[base + d + 32] = f2bf(x2 * cs + x1 * sn);
}

// ---------------------------------------------------------------------------
// MFMA flash attention. Block = 4 waves; one (b,h), 64 q-rows (16 per wave).
// K-tiles of 64 keys. K/V staged via global_load_lds w/ XOR chunk swizzle.
//   s_a = [qa | j2h*qb] . [ka|kb]^T ; s_b = [qa|qb] . [kb|ka]^T  (K=128)
//   mag = sqrt(s_a^2+s_b^2+1e-8)/8 ; causal ; online softmax ; O += P.V
// V supplied transposed: vt[b][c=h*64+d][s].
// ---------------------------------------------------------------------------
__global__ __launch_bounds__(256) void attn_mfma(
    const u16* __restrict__ qa, const u16* __restrict__ qb,
    const u16* __restrict__ ka, const u16* __restrict__ kb,
    const u16* __restrict__ vat, const u16* __restrict__ vbt,
    const float* __restrict__ thetas,
    u16* __restrict__ oa, u16* __restrict__ ob)
{
    __shared__ u16 sKa[64][64];
    __shared__ u16 sKb[64][64];
    __shared__ u16 sVa[64][64];
    __shared__ u16 sVb[64][64];
    __shared__ u16 sP[4][16][72];   // wave-private P, stride 72 hw (16B-aligned rows)

    const int t    = threadIdx.x;
    const int lane = t & 63;
    const int w    = t >> 6;
    const int L15  = lane & 15;
    const int quad = lane >> 4;

    // work-balanced mapping: bid<256 -> qt=15..8 ; bid>=256 -> qt=0..7
    const int bid  = blockIdx.x;
    const int aa   = (bid >> 5) & 7;
    const int qt   = (bid >> 8) ? aa : (15 - aa);
    const int bh   = bid & 31;
    const int h    = bh & 15;
    const int b    = bh >> 4;

    const float j2h = sinf(2.0f * thetas[h]) - 1.0f;

    // ---- Q fragments (A-operand: m=lane&15, k=quad*8+j), 2 slices of 32 ----
    const int   qrow  = qt*64 + w*16 + L15;
    const size_t qbase = (size_t)(b*SEQ + qrow) * EMB + h*DH;
    short8 fqa[2], fqb[2], fjqb[2];
    fqa[0] = *(const short8*)(qa + qbase + quad*8);
    fqa[1] = *(const short8*)(qa + qbase + 32 + quad*8);
    fqb[0] = *(const short8*)(qb + qbase + quad*8);
    fqb[1] = *(const short8*)(qb + qbase + 32 + quad*8);
    #pragma unroll
    for (int s2 = 0; s2 < 2; ++s2) {
        short8 src = fqb[s2], dst;
        #pragma unroll
        for (int j = 0; j < 8; ++j)
            dst[j] = (short)f2bf(bf2f((u16)src[j]) * j2h);
        fjqb[s2] = dst;
    }

    f32x4 acc_a[4] = {};
    f32x4 acc_b[4] = {};
    float m_run[4] = {-1e30f, -1e30f, -1e30f, -1e30f};
    float l_run[4] = {0.f, 0.f, 0.f, 0.f};

    const int subrow = lane >> 3;
    const int g      = (lane & 7) ^ subrow;
    const int swz    = L15 & 7;        // read-side swizzle key

    for (int kt = 0; kt <= qt; ++kt) {
        __syncthreads();
        #pragma unroll
        for (int i = 0; i < 2; ++i) {
            const int row = w*16 + i*8 + subrow;
            const int ldsoff = (w*16 + i*8) * 128;
            const size_t ktok = (size_t)(b*SEQ + kt*64 + row);
            async_copy16((const char*)ka + ktok*2048 + h*128 + g*16,
                         (char*)&sKa[0][0] + ldsoff);
            async_copy16((const char*)kb + ktok*2048 + h*128 + g*16,
                         (char*)&sKb[0][0] + ldsoff);
            const size_t vrow = (size_t)b*1048576 + (size_t)(h*64 + row)*1024 + kt*64;
            async_copy16((const char*)vat + vrow*2 + g*16,
                         (char*)&sVa[0][0] + ldsoff);
            async_copy16((const char*)vbt + vrow*2 + g*16,
                         (char*)&sVb[0][0] + ldsoff);
        }
        __syncthreads();

        // ---- scores ----
        f32x4 sa[4] = {}, sb[4] = {};
        #pragma unroll
        for (int n = 0; n < 4; ++n) {
            const u16* rKa = &sKa[n*16 + L15][0];
            const u16* rKb = &sKb[n*16 + L15][0];
            short8 ka0 = *(const short8*)(rKa + (( quad      ^ swz) << 3));
            short8 ka1 = *(const short8*)(rKa + (((4 + quad) ^ swz) << 3));
            short8 kb0 = *(const short8*)(rKb + (( quad      ^ swz) << 3));
            short8 kb1 = *(const short8*)(rKb + (((4 + quad) ^ swz) << 3));
            sa[n] = __builtin_amdgcn_mfma_f32_16x16x32_bf16(fqa[0],  ka0, sa[n], 0, 0, 0);
            sa[n] = __builtin_amdgcn_mfma_f32_16x16x32_bf16(fqa[1],  ka1, sa[n], 0, 0, 0);
            sa[n] = __builtin_amdgcn_mfma_f32_16x16x32_bf16(fjqb[0], kb0, sa[n], 0, 0, 0);
            sa[n] = __builtin_amdgcn_mfma_f32_16x16x32_bf16(fjqb[1], kb1, sa[n], 0, 0, 0);
            sb[n] = __builtin_amdgcn_mfma_f32_16x16x32_bf16(fqa[0],  kb0, sb[n], 0, 0, 0);
            sb[n] = __builtin_amdgcn_mfma_f32_16x16x32_bf16(fqa[1],  kb1, sb[n], 0, 0, 0);
            sb[n] = __builtin_amdgcn_mfma_f32_16x16x32_bf16(fqb[0],  ka0, sb[n], 0, 0, 0);
            sb[n] = __builtin_amdgcn_mfma_f32_16x16x32_bf16(fqb[1],  ka1, sb[n], 0, 0, 0);
        }

        // ---- magnitude + causal mask ----
        float mag[4][4];
        #pragma unroll
        for (int n = 0; n < 4; ++n)
            #pragma unroll
            for (int r = 0; r < 4; ++r) {
                const float A = sa[n][r], B = sb[n][r];
                mag[n][r] = sqrtf(A*A + B*B + 1e-8f) * 0.125f;
            }
        if (kt == qt) {
            #pragma unroll
            for (int n = 0; n < 4; ++n)
                #pragma unroll
                for (int r = 0; r < 4; ++r)
                    if (n*16 + L15 > w*16 + quad*4 + r) mag[n][r] = -1e9f;
        }

        // ---- online softmax ----
        float rmax[4], psum[4], alpha[4];
        #pragma unroll
        for (int r = 0; r < 4; ++r) {
            float mx = fmaxf(fmaxf(mag[0][r], mag[1][r]), fmaxf(mag[2][r], mag[3][r]));
            #pragma unroll
            for (int off = 8; off >= 1; off >>= 1)
                mx = fmaxf(mx, __shfl_xor(mx, off, 64));
            rmax[r] = mx;
        }
        float p[4][4];
        #pragma unroll
        for (int r = 0; r < 4; ++r) {
            const float m_new = fmaxf(m_run[r], rmax[r]);
            alpha[r] = expf(m_run[r] - m_new);
            m_run[r] = m_new;
            float ps = 0.f;
            #pragma unroll
            for (int n = 0; n < 4; ++n) {
                p[n][r] = expf(mag[n][r] - m_new);
                ps += p[n][r];
            }
            #pragma unroll
            for (int off = 8; off >= 1; off >>= 1)
                ps += __shfl_xor(ps, off, 64);
            psum[r] = ps;
            l_run[r] = l_run[r] * alpha[r] + psum[r];
        }
        #pragma unroll
        for (int n = 0; n < 4; ++n)
            #pragma unroll
            for (int r = 0; r < 4; ++r) {
                acc_a[n][r] *= alpha[r];
                acc_b[n][r] *= alpha[r];
            }

        // ---- P -> LDS (wave-private), re-enter as A-operand ----
        #pragma unroll
        for (int n = 0; n < 4; ++n)
            #pragma unroll
            for (int r = 0; r < 4; ++r)
                sP[w][quad*4 + r][n*16 + L15] = f2bf(p[n][r]);

        short8 pf0 = *(const short8*)&sP[w][L15][quad*8];
        short8 pf1 = *(const short8*)&sP[w][L15][32 + quad*8];

        // ---- PV ----
        #pragma unroll
        for (int n = 0; n < 4; ++n) {
            const u16* rVa = &sVa[n*16 + L15][0];
            const u16* rVb = &sVb[n*16 + L15][0];
            short8 va0 = *(const short8*)(rVa + (( quad      ^ swz) << 3));
            short8 va1 = *(const short8*)(rVa + (((4 + quad) ^ swz) << 3));
            short8 vb0 = *(const short8*)(rVb + (( quad      ^ swz) << 3));
            short8 vb1 = *(const short8*)(rVb + (((4 + quad) ^ swz) << 3));
            acc_a[n] = __builtin_amdgcn_mfma_f32_16x16x32_bf16(pf0, va0, acc_a[n], 0, 0, 0);
            acc_a[n] = __builtin_amdgcn_mfma_f32_16x16x32_bf16(pf1, va1, acc_a[n], 0, 0, 0);
            acc_b[n] = __builtin_amdgcn_mfma_f32_16x16x32_bf16(pf0, vb0, acc_b[n], 0, 0, 0);
            acc_b[n] = __builtin_amdgcn_mfma_f32_16x16x32_bf16(pf1, vb1, acc_b[n], 0, 0, 0);
        }
    }

    // ---- write out (C layout: row=quad*4+reg, col=n*16+L15) ----
    float inv[4];
    #pragma unroll
    for (int r = 0; r < 4; ++r) inv[r] = 1.0f / l_run[r];
    #pragma unroll
    for (int reg = 0; reg < 4; ++reg) {
        const size_t tok = (size_t)(b*SEQ + qt*64 + w*16 + quad*4 + reg);
        #pragma unroll
        for (int n = 0; n < 4; ++n) {
            const size_t idx = tok*EMB + h*DH + n*16 + L15;
            oa[idx] = f2bf(acc_a[n][reg] * inv[reg]);
            ob[idx] = f2bf(acc_b[n][reg] * inv[reg]);
        }
    }
}

// ---------------------------------------------------------------------------
extern "C" void kernel_launch(void* const* d_in, const int* in_sizes, int n_in,
                              void* d_out, int out_size, void* d_ws, size_t ws_size,
                              hipStream_t stream)
{
    const float* x_q_a  = (const float*)d_in[0];
    const float* x_q_b  = (const float*)d_in[1];
    const float* x_kv_a = (const float*)d_in[2];
    const float* x_kv_b = (const float*)d_in[3];
    const float* theta    = (const float*)d_in[5];
    const float* thetas_h = (const float*)d_in[6];
    const float* q_wa = (const float*)d_in[7];
    const float* q_wb = (const float*)d_in[8];
    const float* q_ba = (const float*)d_in[9];
    const float* q_bb = (const float*)d_in[10];
    const float* k_wa = (const float*)d_in[11];
    const float* k_wb = (const float*)d_in[12];
    const float* k_ba = (const float*)d_in[13];
    const float* k_bb = (const float*)d_in[14];
    const float* v_wa = (const float*)d_in[15];
    const float* v_wb = (const float*)d_in[16];
    const float* v_ba = (const float*)d_in[17];
    const float* v_bb = (const float*)d_in[18];
    const float* o_wa = (const float*)d_in[19];
    const float* o_wb = (const float*)d_in[20];
    const float* o_ba = (const float*)d_in[21];
    const float* o_bb = (const float*)d_in[22];

    u16* W = (u16*)d_ws;
    const size_t XN = (size_t)BSE;
    const size_t WN = (size_t)EMB*EMB;
    u16* xq_a16  = W;
    u16* xq_b16  = W + XN;
    u16* xkv_a16 = W + 2*XN;
    u16* xkv_b16 = W + 3*XN;
    u16* wbase   = W + 4*XN;
    u16* q_wa16  = wbase;
    u16* q_wb16  = wbase + WN;
    u16* k_wa16  = wbase + 2*WN;
    u16* k_wb16  = wbase + 3*WN;
    u16* v_wa16  = wbase + 4*WN;
    u16* v_wb16  = wbase + 5*WN;
    u16* o_wa16  = wbase + 6*WN;
    u16* o_wb16  = wbase + 7*WN;
    u16* q_wbs16 = wbase + 8*WN;
    u16* k_wbs16 = wbase + 9*WN;
    u16* v_wbs16 = wbase + 10*WN;
    u16* o_wbs16 = wbase + 11*WN;
    u16* qkv     = wbase + 12*WN;
    u16* qa16 = qkv;
    u16* qb16 = qkv + XN;
    u16* ka16 = qkv + 2*XN;
    u16* kb16 = qkv + 3*XN;
    u16* vat16 = qkv + 4*XN;   // transposed [b][c][s]
    u16* vbt16 = qkv + 5*XN;
    u16* ao16 = xq_a16;        // alias: xq region free after QKV GEMM
    u16* bo16 = xq_b16;

    float* out_a = (float*)d_out;
    float* out_b = out_a + (size_t)BSE;

    // ---- 1. pack to bf16 ----
    PackArgs pa;
    const float* psrc[16] = { x_q_a, x_q_b, x_kv_a, x_kv_b,
                              q_wa, q_wb, k_wa, k_wb, v_wa, v_wb, o_wa, o_wb,
                              q_wb, k_wb, v_wb, o_wb };
    u16* pdst[16] = { xq_a16, xq_b16, xkv_a16, xkv_b16,
                      q_wa16, q_wb16, k_wa16, k_wb16, v_wa16, v_wb16, o_wa16, o_wb16,
                      q_wbs16, k_wbs16, v_wbs16, o_wbs16 };
    for (int e = 0; e < 16; ++e) {
        pa.src[e] = psrc[e];
        pa.dst[e] = pdst[e];
        pa.n[e]   = (e < 4) ? (int)XN : (int)WN;
        pa.scaled[e] = (e >= 12) ? 1 : 0;
    }
    pack_kernel<<<dim3(XN/(256*4), 16), 256, 0, stream>>>(pa, theta);

    // zero the fp32 output for split-K atomic accumulation (graph-safe async)
    hipMemsetAsync(d_out, 0, (size_t)out_size * sizeof(float), stream);

    // ---- 2. QKV projections: ONE dispatch, 6 segments ----
    GemmArgs g12;
    // seg 0: qa   seg 1: qb   seg 2: ka   seg 3: kb   seg 4: va^T  seg 5: vb^T
    const u16* a1s[6] = { xq_a16, xq_a16, xkv_a16, xkv_a16, xkv_a16, xkv_a16 };
    const u16* a2s[6] = { xq_b16, xq_b16, xkv_b16, xkv_b16, xkv_b16, xkv_b16 };
    const u16* blo[6] = { q_wa16, q_wb16, k_wa16, k_wb16, v_wa16, v_wb16 };
    const u16* bhi[6] = { q_wbs16, q_wa16, k_wbs16, k_wa16, v_wbs16, v_wa16 };
    const float* bia[6] = { q_ba, q_bb, k_ba, k_bb, v_ba, v_bb };
    void* dsts[6] = { qa16, qb16, ka16, kb16, vat16, vbt16 };
    const int modes[6] = { 0, 0, 0, 0, 2, 2 };
    for (int s = 0; s < 6; ++s) {
        g12.A1s[s] = a1s[s]; g12.A2s[s] = a2s[s];
        g12.Blo[s] = blo[s]; g12.Bhi[s] = bhi[s];
        g12.bias[s] = bia[s]; g12.dst[s] = dsts[s]; g12.mode[s] = modes[s];
    }
    for (int s = 6; s < 8; ++s) {  // unused slots
        g12.A1s[s] = a1s[0]; g12.A2s[s] = a2s[0];
        g12.Blo[s] = blo[0]; g12.Bhi[s] = bhi[0];
        g12.bias[s] = bia[0]; g12.dst[s] = dsts[0]; g12.mode[s] = 0;
    }
    mfma_gemm<1><<<dim3(MROWS/128, 48), 256, 0, stream>>>(g12);

    // ---- 3. RoPE (q/k) ----
    rope_kernel<<<dim3((BATCH*SEQ*NH*32)/256, 4), 256, 0, stream>>>(qa16, qb16, ka16, kb16);

    // ---- 4. attention (MFMA flash) ----
    attn_mfma<<<BATCH*NH*(SEQ/64), 256, 0, stream>>>(qa16, qb16, ka16, kb16,
                                                     vat16, vbt16, thetas_h, ao16, bo16);

    // ---- 5. output projection: split-K=2, fp32 atomic accumulation ----
    GemmArgs g3;
    for (int s = 0; s < 8; ++s) {
        g3.A1s[s] = ao16; g3.A2s[s] = bo16;
        g3.Blo[s] = o_wa16; g3.Bhi[s] = o_wbs16;
        g3.bias[s] = o_ba; g3.dst[s] = out_a; g3.mode[s] = 1;
    }
    g3.Blo[1] = o_wb16; g3.Bhi[1] = o_wa16; g3.bias[1] = o_bb; g3.dst[1] = out_b;
    mfma_gemm<2><<<dim3(MROWS/128, 16, 2), 256, 0, stream>>>(g3);
}

// Round 8
// 308.098 us; speedup vs baseline: 5.2973x; 1.0766x over previous
//
#include <hip/hip_runtime.h>
#include <math.h>
#include <stdint.h>

#define BATCH 2
#define SEQ   1024
#define EMB   1024
#define NH    16
#define DH    64
#define BSE   (BATCH*SEQ*EMB)   /* 2097152 elements per (B,S,E) tensor */
#define MROWS (BATCH*SEQ)       /* 2048 */

typedef unsigned short u16;
typedef __attribute__((ext_vector_type(8))) short short8;
typedef __attribute__((ext_vector_type(4))) float f32x4;

__device__ __forceinline__ float bf2f(u16 u) {
    return __uint_as_float(((unsigned int)u) << 16);
}
__device__ __forceinline__ u16 f2bf(float f) {
    unsigned int x = __float_as_uint(f);
    x += 0x7FFFu + ((x >> 16) & 1u);   // round-to-nearest-even
    return (u16)(x >> 16);
}

__device__ __forceinline__ void async_copy16(const void* g, void* l) {
    __builtin_amdgcn_global_load_lds(
        (const __attribute__((address_space(1))) unsigned int*)g,
        (__attribute__((address_space(3))) unsigned int*)l,
        16, 0, 0);
}

// ---------------------------------------------------------------------------
// Pack: fp32 -> bf16, 20 slots of exactly 1M elems each (no idle blocks).
// x tensors (2M) occupy 2 slots; scaled slots multiply by j2 = sin(2θ)-1.
// grid = (1024, 20), 4 elems/thread.
// ---------------------------------------------------------------------------
struct PackArgs {
    const float* src[20];
    u16*         dst[20];
    int          scaled[20];
};

__global__ __launch_bounds__(256) void pack_kernel(PackArgs pa, const float* __restrict__ theta)
{
    const int e = blockIdx.y;
    const size_t i = ((size_t)blockIdx.x * 256 + threadIdx.x) * 4;
    float sc = 1.0f;
    if (pa.scaled[e]) sc = sinf(2.0f * theta[0]) - 1.0f;
    float4 v = *(const float4*)(pa.src[e] + i);
    ushort4 o;
    o.x = f2bf(v.x * sc); o.y = f2bf(v.y * sc);
    o.z = f2bf(v.z * sc); o.w = f2bf(v.w * sc);
    *(ushort4*)(pa.dst[e] + i) = o;
}

// ---------------------------------------------------------------------------
// MFMA bf16 GEMM with virtual K-concat (K=2048), up to 8 N-segments of 1024.
//   C[m][c] = sum_k A1[m][k]*Blo[c][k] + A2[m][k]*Bhi[c][k] + bias[c]
// mode: 0 = bf16 [m][c] store,
//       1 = fp32 atomicAdd [m][c] (split-K; bias added by ko==0 only),
//       2 = bf16 transposed store dst[b][c][s]  (V^T)
// SPLITK=1: one block does full K. SPLITK=2: blockIdx.z selects K-half.
// 128x128 tile, BK=32, 4 waves, 16x16x32 MFMA, global_load_lds width-16.
// ---------------------------------------------------------------------------
struct GemmArgs {
    const u16*   A1s[8];
    const u16*   A2s[8];
    const u16*   Blo[8];
    const u16*   Bhi[8];
    const float* bias[8];
    void*        dst[8];
    int          mode[8];
};

template<int SPLITK>
__global__ __launch_bounds__(256) void mfma_gemm(GemmArgs ga)
{
    __shared__ u16 sA[128][32];
    __shared__ u16 sB[128][32];

    const int t    = threadIdx.x;
    const int lane = t & 63;
    const int w    = t >> 6;
    const int wx   = w & 1;
    const int wy   = w >> 1;
    const int n0   = blockIdx.y * 128;   // n-tile = slow index
    const int m0   = blockIdx.x * 128;   // m-tile = fast index
    const int ko   = (SPLITK == 2) ? blockIdx.z : 0;
    const int seg  = n0 >> 10;
    const int nloc = n0 & 1023;

    const int srow = t >> 2;          // staging row within 64-row round
    const int sb   = (t & 3) * 16;    // staging byte offset within 64-B row

    f32x4 acc[4][4] = {};

    const char* A1 = (const char*)ga.A1s[seg];
    const char* A2 = (const char*)ga.A2s[seg];
    const char* Bl = (const char*)ga.Blo[seg];
    const char* Bh = (const char*)ga.Bhi[seg];
    if (SPLITK == 2 && ko) { A1 = A2; Bl = Bh; }

    const int frow = lane & 15;
    const int quad = lane >> 4;

    const int NKT = (SPLITK == 2) ? 32 : 64;
    for (int kt = 0; kt < NKT; ++kt) {
        const char* As = (SPLITK == 1 && (kt & 32)) ? A2 : A1;
        const char* Bs = (SPLITK == 1 && (kt & 32)) ? Bh : Bl;
        const size_t kbyte = (size_t)(kt & 31) * 64;

        __syncthreads();
        #pragma unroll
        for (int r = 0; r < 2; ++r) {
            const int row = r*64 + srow;
            const int ldsoff = (r*64 + w*16) * 64;
            async_copy16(As + (size_t)(m0 + row)*2048 + kbyte + sb,
                         (char*)&sA[0][0] + ldsoff);
            async_copy16(Bs + (size_t)(nloc + row)*2048 + kbyte + sb,
                         (char*)&sB[0][0] + ldsoff);
        }
        __syncthreads();

        short8 af[4], bfr[4];
        #pragma unroll
        for (int i = 0; i < 4; ++i)
            af[i] = *(const short8*)&sA[wy*64 + i*16 + frow][quad*8];
        #pragma unroll
        for (int j = 0; j < 4; ++j)
            bfr[j] = *(const short8*)&sB[wx*64 + j*16 + frow][quad*8];

        #pragma unroll
        for (int i = 0; i < 4; ++i)
            #pragma unroll
            for (int j = 0; j < 4; ++j)
                acc[i][j] = __builtin_amdgcn_mfma_f32_16x16x32_bf16(
                                af[i], bfr[j], acc[i][j], 0, 0, 0);
    }

    // ---- epilogue: C/D layout col=lane&15, row=quad*4+reg ----
    const float* bias = ga.bias[seg];
    const int mode = ga.mode[seg];

    #pragma unroll
    for (int j = 0; j < 4; ++j) {
        const int c = nloc + wx*64 + j*16 + frow;
        const float bv = (SPLITK == 2 && ko) ? 0.0f : bias[c];
        #pragma unroll
        for (int i = 0; i < 4; ++i) {
            #pragma unroll
            for (int reg = 0; reg < 4; ++reg) {
                const int m = m0 + wy*64 + i*16 + quad*4 + reg;
                const float val = acc[i][j][reg] + bv;
                if (mode == 1) {
                    if (SPLITK == 2)
                        atomicAdd((float*)ga.dst[seg] + (size_t)m*1024 + c, val);
                    else
                        ((float*)ga.dst[seg])[(size_t)m*1024 + c] = val;
                } else if (mode == 2) {
                    // V^T: [b][c][s], b = m>>10, s = m&1023
                    ((u16*)ga.dst[seg])[((size_t)(m >> 10) << 20) + (size_t)c*1024 + (m & 1023)] = f2bf(val);
                } else {
                    ((u16*)ga.dst[seg])[(size_t)m*1024 + c] = f2bf(val);
                }
            }
        }
    }
}

// ---------------------------------------------------------------------------
// RoPE, in place on (B,S,E) bf16; pair (d, d+32) within each head.
// ---------------------------------------------------------------------------
__global__ __launch_bounds__(256) void rope_kernel(
    u16* qa, u16* qb, u16* ka, u16* kb)
{
    u16* p;
    switch (blockIdx.y) {
        case 0:  p = qa; break;
        case 1:  p = qb; break;
        case 2:  p = ka; break;
        default: p = kb; break;
    }
    const int i   = blockIdx.x * 256 + threadIdx.x;
    const int d   = i & 31;
    const int hh  = (i >> 5) & (NH - 1);
    const int row = i >> 9;
    const int s   = row & (SEQ - 1);
    const size_t base = (size_t)row * EMB + hh * DH;

    float x1 = bf2f(p[base + d]);
    float x2 = bf2f(p[base + d + 32]);
    const float invf_rev = expf(-(float)d * 0.28782313662425576f) * 0.15915494309189535f;
    float rev = (float)s * invf_rev;
    rev -= floorf(rev);
    const float sn = __builtin_amdgcn_sinf(rev);
    const float cs = __builtin_amdgcn_cosf(rev);
    p[base + d]      = f2bf(x1 * cs - x2 * sn);
    p[base + d + 32] = f2bf(x2 * cs + x1 * sn);
}

// ---------------------------------------------------------------------------
// MFMA flash attention, fixed-max softmax (scores are magnitudes >= 0 and
// bounded: |s| <= |q||k|(1+|j2h|) -> mag <= ~24 -> exp fits fp32 easily).
//   p = exp2(1.4427*mag) (masked -> 0); l accumulated lane-locally, reduced
//   once after the K-loop. No running max / alpha rescale needed.
// ---------------------------------------------------------------------------
__global__ __launch_bounds__(256) void attn_mfma(
    const u16* __restrict__ qa, const u16* __restrict__ qb,
    const u16* __restrict__ ka, const u16* __restrict__ kb,
    const u16* __restrict__ vat, const u16* __restrict__ vbt,
    const float* __restrict__ thetas,
    u16* __restrict__ oa, u16* __restrict__ ob)
{
    __shared__ u16 sKa[64][64];
    __shared__ u16 sKb[64][64];
    __shared__ u16 sVa[64][64];
    __shared__ u16 sVb[64][64];
    __shared__ u16 sP[4][16][72];   // wave-private P, stride 72 hw

    const int t    = threadIdx.x;
    const int lane = t & 63;
    const int w    = t >> 6;
    const int L15  = lane & 15;
    const int quad = lane >> 4;

    // work-balanced mapping: bid<256 -> qt=15..8 ; bid>=256 -> qt=0..7
    const int bid  = blockIdx.x;
    const int aa   = (bid >> 5) & 7;
    const int qt   = (bid >> 8) ? aa : (15 - aa);
    const int bh   = bid & 31;
    const int h    = bh & 15;
    const int b    = bh >> 4;

    const float j2h = sinf(2.0f * thetas[h]) - 1.0f;

    // ---- Q fragments (A-operand: m=lane&15, k=quad*8+j), 2 slices of 32 ----
    const int   qrow  = qt*64 + w*16 + L15;
    const size_t qbase = (size_t)(b*SEQ + qrow) * EMB + h*DH;
    short8 fqa[2], fqb[2], fjqb[2];
    fqa[0] = *(const short8*)(qa + qbase + quad*8);
    fqa[1] = *(const short8*)(qa + qbase + 32 + quad*8);
    fqb[0] = *(const short8*)(qb + qbase + quad*8);
    fqb[1] = *(const short8*)(qb + qbase + 32 + quad*8);
    #pragma unroll
    for (int s2 = 0; s2 < 2; ++s2) {
        short8 src = fqb[s2], dst;
        #pragma unroll
        for (int j = 0; j < 8; ++j)
            dst[j] = (short)f2bf(bf2f((u16)src[j]) * j2h);
        fjqb[s2] = dst;
    }

    f32x4 acc_a[4] = {};
    f32x4 acc_b[4] = {};
    float l_lane[4] = {0.f, 0.f, 0.f, 0.f};

    const int subrow = lane >> 3;
    const int g      = (lane & 7) ^ subrow;
    const int swz    = L15 & 7;        // read-side swizzle key

    for (int kt = 0; kt <= qt; ++kt) {
        __syncthreads();
        #pragma unroll
        for (int i = 0; i < 2; ++i) {
            const int row = w*16 + i*8 + subrow;
            const int ldsoff = (w*16 + i*8) * 128;
            const size_t ktok = (size_t)(b*SEQ + kt*64 + row);
            async_copy16((const char*)ka + ktok*2048 + h*128 + g*16,
                         (char*)&sKa[0][0] + ldsoff);
            async_copy16((const char*)kb + ktok*2048 + h*128 + g*16,
                         (char*)&sKb[0][0] + ldsoff);
            const size_t vrow = (size_t)b*1048576 + (size_t)(h*64 + row)*1024 + kt*64;
            async_copy16((const char*)vat + vrow*2 + g*16,
                         (char*)&sVa[0][0] + ldsoff);
            async_copy16((const char*)vbt + vrow*2 + g*16,
                         (char*)&sVb[0][0] + ldsoff);
        }
        __syncthreads();

        // ---- scores ----
        f32x4 sa[4] = {}, sb[4] = {};
        #pragma unroll
        for (int n = 0; n < 4; ++n) {
            const u16* rKa = &sKa[n*16 + L15][0];
            const u16* rKb = &sKb[n*16 + L15][0];
            short8 ka0 = *(const short8*)(rKa + (( quad      ^ swz) << 3));
            short8 ka1 = *(const short8*)(rKa + (((4 + quad) ^ swz) << 3));
            short8 kb0 = *(const short8*)(rKb + (( quad      ^ swz) << 3));
            short8 kb1 = *(const short8*)(rKb + (((4 + quad) ^ swz) << 3));
            sa[n] = __builtin_amdgcn_mfma_f32_16x16x32_bf16(fqa[0],  ka0, sa[n], 0, 0, 0);
            sa[n] = __builtin_amdgcn_mfma_f32_16x16x32_bf16(fqa[1],  ka1, sa[n], 0, 0, 0);
            sa[n] = __builtin_amdgcn_mfma_f32_16x16x32_bf16(fjqb[0], kb0, sa[n], 0, 0, 0);
            sa[n] = __builtin_amdgcn_mfma_f32_16x16x32_bf16(fjqb[1], kb1, sa[n], 0, 0, 0);
            sb[n] = __builtin_amdgcn_mfma_f32_16x16x32_bf16(fqa[0],  kb0, sb[n], 0, 0, 0);
            sb[n] = __builtin_amdgcn_mfma_f32_16x16x32_bf16(fqa[1],  kb1, sb[n], 0, 0, 0);
            sb[n] = __builtin_amdgcn_mfma_f32_16x16x32_bf16(fqb[0],  ka0, sb[n], 0, 0, 0);
            sb[n] = __builtin_amdgcn_mfma_f32_16x16x32_bf16(fqb[1],  ka1, sb[n], 0, 0, 0);
        }

        // ---- p = exp(mag) (fixed max = 0; causal mask -> 0) ----
        float p[4][4];
        if (kt == qt) {
            #pragma unroll
            for (int n = 0; n < 4; ++n)
                #pragma unroll
                for (int r = 0; r < 4; ++r) {
                    const float A = sa[n][r], B = sb[n][r];
                    const float mag = __builtin_amdgcn_sqrtf(A*A + B*B + 1e-8f) * 0.125f;
                    const bool masked = (n*16 + L15) > (w*16 + quad*4 + r);
                    p[n][r] = masked ? 0.0f
                                     : __builtin_amdgcn_exp2f(mag * 1.44269504f);
                }
        } else {
            #pragma unroll
            for (int n = 0; n < 4; ++n)
                #pragma unroll
                for (int r = 0; r < 4; ++r) {
                    const float A = sa[n][r], B = sb[n][r];
                    const float mag = __builtin_amdgcn_sqrtf(A*A + B*B + 1e-8f) * 0.125f;
                    p[n][r] = __builtin_amdgcn_exp2f(mag * 1.44269504f);
                }
        }
        #pragma unroll
        for (int r = 0; r < 4; ++r)
            l_lane[r] += (p[0][r] + p[1][r]) + (p[2][r] + p[3][r]);

        // ---- P -> LDS (wave-private), re-enter as A-operand ----
        #pragma unroll
        for (int n = 0; n < 4; ++n)
            #pragma unroll
            for (int r = 0; r < 4; ++r)
                sP[w][quad*4 + r][n*16 + L15] = f2bf(p[n][r]);

        short8 pf0 = *(const short8*)&sP[w][L15][quad*8];
        short8 pf1 = *(const short8*)&sP[w][L15][32 + quad*8];

        // ---- PV ----
        #pragma unroll
        for (int n = 0; n < 4; ++n) {
            const u16* rVa = &sVa[n*16 + L15][0];
            const u16* rVb = &sVb[n*16 + L15][0];
            short8 va0 = *(const short8*)(rVa + (( quad      ^ swz) << 3));
            short8 va1 = *(const short8*)(rVa + (((4 + quad) ^ swz) << 3));
            short8 vb0 = *(const short8*)(rVb + (( quad      ^ swz) << 3));
            short8 vb1 = *(const short8*)(rVb + (((4 + quad) ^ swz) << 3));
            acc_a[n] = __builtin_amdgcn_mfma_f32_16x16x32_bf16(pf0, va0, acc_a[n], 0, 0, 0);
            acc_a[n] = __builtin_amdgcn_mfma_f32_16x16x32_bf16(pf1, va1, acc_a[n], 0, 0, 0);
            acc_b[n] = __builtin_amdgcn_mfma_f32_16x16x32_bf16(pf0, vb0, acc_b[n], 0, 0, 0);
            acc_b[n] = __builtin_amdgcn_mfma_f32_16x16x32_bf16(pf1, vb1, acc_b[n], 0, 0, 0);
        }
    }

    // ---- final l reduction (row lives across the 16 lanes of a quad) ----
    float inv[4];
    #pragma unroll
    for (int r = 0; r < 4; ++r) {
        float l = l_lane[r];
        #pragma unroll
        for (int off = 8; off >= 1; off >>= 1)
            l += __shfl_xor(l, off, 64);
        inv[r] = 1.0f / l;
    }

    // ---- write out (C layout: row=quad*4+reg, col=n*16+L15) ----
    #pragma unroll
    for (int reg = 0; reg < 4; ++reg) {
        const size_t tok = (size_t)(b*SEQ + qt*64 + w*16 + quad*4 + reg);
        #pragma unroll
        for (int n = 0; n < 4; ++n) {
            const size_t idx = tok*EMB + h*DH + n*16 + L15;
            oa[idx] = f2bf(acc_a[n][reg] * inv[reg]);
            ob[idx] = f2bf(acc_b[n][reg] * inv[reg]);
        }
    }
}

// ---------------------------------------------------------------------------
extern "C" void kernel_launch(void* const* d_in, const int* in_sizes, int n_in,
                              void* d_out, int out_size, void* d_ws, size_t ws_size,
                              hipStream_t stream)
{
    const float* x_q_a  = (const float*)d_in[0];
    const float* x_q_b  = (const float*)d_in[1];
    const float* x_kv_a = (const float*)d_in[2];
    const float* x_kv_b = (const float*)d_in[3];
    const float* theta    = (const float*)d_in[5];
    const float* thetas_h = (const float*)d_in[6];
    const float* q_wa = (const float*)d_in[7];
    const float* q_wb = (const float*)d_in[8];
    const float* q_ba = (const float*)d_in[9];
    const float* q_bb = (const float*)d_in[10];
    const float* k_wa = (const float*)d_in[11];
    const float* k_wb = (const float*)d_in[12];
    const float* k_ba = (const float*)d_in[13];
    const float* k_bb = (const float*)d_in[14];
    const float* v_wa = (const float*)d_in[15];
    const float* v_wb = (const float*)d_in[16];
    const float* v_ba = (const float*)d_in[17];
    const float* v_bb = (const float*)d_in[18];
    const float* o_wa = (const float*)d_in[19];
    const float* o_wb = (const float*)d_in[20];
    const float* o_ba = (const float*)d_in[21];
    const float* o_bb = (const float*)d_in[22];

    u16* W = (u16*)d_ws;
    const size_t XN = (size_t)BSE;
    const size_t WN = (size_t)EMB*EMB;
    u16* xq_a16  = W;
    u16* xq_b16  = W + XN;
    u16* xkv_a16 = W + 2*XN;
    u16* xkv_b16 = W + 3*XN;
    u16* wbase   = W + 4*XN;
    u16* q_wa16  = wbase;
    u16* q_wb16  = wbase + WN;
    u16* k_wa16  = wbase + 2*WN;
    u16* k_wb16  = wbase + 3*WN;
    u16* v_wa16  = wbase + 4*WN;
    u16* v_wb16  = wbase + 5*WN;
    u16* o_wa16  = wbase + 6*WN;
    u16* o_wb16  = wbase + 7*WN;
    u16* q_wbs16 = wbase + 8*WN;
    u16* k_wbs16 = wbase + 9*WN;
    u16* v_wbs16 = wbase + 10*WN;
    u16* o_wbs16 = wbase + 11*WN;
    u16* qkv     = wbase + 12*WN;
    u16* qa16 = qkv;
    u16* qb16 = qkv + XN;
    u16* ka16 = qkv + 2*XN;
    u16* kb16 = qkv + 3*XN;
    u16* vat16 = qkv + 4*XN;   // transposed [b][c][s]
    u16* vbt16 = qkv + 5*XN;
    u16* ao16 = xq_a16;        // alias: xq region free after QKV GEMM
    u16* bo16 = xq_b16;

    float* out_a = (float*)d_out;
    float* out_b = out_a + (size_t)BSE;

    // ---- 1. pack to bf16 (20 fully-active slots of 1M elems) ----
    PackArgs pa;
    int si = 0;
    auto add = [&](const float* s, u16* d, int scaled, int chunks) {
        for (int c = 0; c < chunks; ++c) {
            pa.src[si] = s + (size_t)c * WN;
            pa.dst[si] = d + (size_t)c * WN;
            pa.scaled[si] = scaled;
            ++si;
        }
    };
    add(x_q_a,  xq_a16,  0, 2);
    add(x_q_b,  xq_b16,  0, 2);
    add(x_kv_a, xkv_a16, 0, 2);
    add(x_kv_b, xkv_b16, 0, 2);
    add(q_wa, q_wa16, 0, 1);  add(q_wb, q_wb16, 0, 1);
    add(k_wa, k_wa16, 0, 1);  add(k_wb, k_wb16, 0, 1);
    add(v_wa, v_wa16, 0, 1);  add(v_wb, v_wb16, 0, 1);
    add(o_wa, o_wa16, 0, 1);  add(o_wb, o_wb16, 0, 1);
    add(q_wb, q_wbs16, 1, 1); add(k_wb, k_wbs16, 1, 1);
    add(v_wb, v_wbs16, 1, 1); add(o_wb, o_wbs16, 1, 1);
    pack_kernel<<<dim3(WN/1024, 20), 256, 0, stream>>>(pa, theta);

    // zero the fp32 output for split-K atomic accumulation (graph-safe async)
    hipMemsetAsync(d_out, 0, (size_t)out_size * sizeof(float), stream);

    // ---- 2. QKV projections: ONE dispatch, 6 segments ----
    GemmArgs g12;
    const u16* a1s[6] = { xq_a16, xq_a16, xkv_a16, xkv_a16, xkv_a16, xkv_a16 };
    const u16* a2s[6] = { xq_b16, xq_b16, xkv_b16, xkv_b16, xkv_b16, xkv_b16 };
    const u16* blo[6] = { q_wa16, q_wb16, k_wa16, k_wb16, v_wa16, v_wb16 };
    const u16* bhi[6] = { q_wbs16, q_wa16, k_wbs16, k_wa16, v_wbs16, v_wa16 };
    const float* bia[6] = { q_ba, q_bb, k_ba, k_bb, v_ba, v_bb };
    void* dsts[6] = { qa16, qb16, ka16, kb16, vat16, vbt16 };
    const int modes[6] = { 0, 0, 0, 0, 2, 2 };
    for (int s = 0; s < 6; ++s) {
        g12.A1s[s] = a1s[s]; g12.A2s[s] = a2s[s];
        g12.Blo[s] = blo[s]; g12.Bhi[s] = bhi[s];
        g12.bias[s] = bia[s]; g12.dst[s] = dsts[s]; g12.mode[s] = modes[s];
    }
    for (int s = 6; s < 8; ++s) {
        g12.A1s[s] = a1s[0]; g12.A2s[s] = a2s[0];
        g12.Blo[s] = blo[0]; g12.Bhi[s] = bhi[0];
        g12.bias[s] = bia[0]; g12.dst[s] = dsts[0]; g12.mode[s] = 0;
    }
    mfma_gemm<1><<<dim3(MROWS/128, 48), 256, 0, stream>>>(g12);

    // ---- 3. RoPE (q/k) ----
    rope_kernel<<<dim3((BATCH*SEQ*NH*32)/256, 4), 256, 0, stream>>>(qa16, qb16, ka16, kb16);

    // ---- 4. attention (MFMA flash, fixed-max softmax) ----
    attn_mfma<<<BATCH*NH*(SEQ/64), 256, 0, stream>>>(qa16, qb16, ka16, kb16,
                                                     vat16, vbt16, thetas_h, ao16, bo16);

    // ---- 5. output projection: split-K=2, fp32 atomic accumulation ----
    GemmArgs g3;
    for (int s = 0; s < 8; ++s) {
        g3.A1s[s] = ao16; g3.A2s[s] = bo16;
        g3.Blo[s] = o_wa16; g3.Bhi[s] = o_wbs16;
        g3.bias[s] = o_ba; g3.dst[s] = out_a; g3.mode[s] = 1;
    }
    g3.Blo[1] = o_wb16; g3.Bhi[1] = o_wa16; g3.bias[1] = o_bb; g3.dst[1] = out_b;
    mfma_gemm<2><<<dim3(MROWS/128, 16, 2), 256, 0, stream>>>(g3);
}